// Round 3
// baseline (2572.432 us; speedup 1.0000x reference)
//
#include <hip/hip_runtime.h>

#define LEAK 0.01f

// ---- float <-> orderable-uint encoding for atomic min on floats ----
__device__ __forceinline__ unsigned int fmin_encode(float x) {
    unsigned int u = __float_as_uint(x);
    return (u & 0x80000000u) ? ~u : (u | 0x80000000u);
}
__device__ __forceinline__ float fmin_decode(unsigned int k) {
    unsigned int u = (k & 0x80000000u) ? (k ^ 0x80000000u) : ~k;
    return __uint_as_float(u);
}

__device__ __forceinline__ float lrelu(float v) {
    return v >= 0.f ? v : LEAK * v;
}

// x0[b,n,:] = [float(nf0), float(nf1), action]
__global__ __launch_bounds__(256) void node_init_kernel(
    const int* __restrict__ nf, const float* __restrict__ act,
    float* __restrict__ x0, int BN) {
    int tid = blockIdx.x * blockDim.x + threadIdx.x;
    if (tid >= BN) return;
    x0[tid * 3 + 0] = (float)nf[tid * 2 + 0];
    x0[tid * 3 + 1] = (float)nf[tid * 2 + 1];
    x0[tid * 3 + 2] = act[tid];
}

// One thread per edge: m=[x[dst](D), x[src](D), ea] -> Lin(2D+1,8) -> lrelu
// -> Lin(8,8) -> atomic scatter-min (orderable-uint) at dst.
// NOTE: edge_index arrives as int32 (JAX x64 disabled; harness: integer -> int*).
template <int D>
__global__ __launch_bounds__(256) void edge_conv_kernel(
    const float* __restrict__ x, const int* __restrict__ ei,
    const float* __restrict__ ea,
    const float* __restrict__ W1, const float* __restrict__ b1,
    const float* __restrict__ W2, const float* __restrict__ b2,
    unsigned int* __restrict__ agg, int E, int N, int B) {
    int tid = blockIdx.x * blockDim.x + threadIdx.x;
    if (tid >= B * E) return;
    int b = tid / E;
    int e = tid - b * E;
    const int* eb = ei + (size_t)b * 2 * E;
    int s = eb[e];          // row 0 = src (x_j)
    int d = eb[E + e];      // row 1 = dst (x_i, scatter target)
    const float* xi = x + ((size_t)b * N + d) * D;
    const float* xj = x + ((size_t)b * N + s) * D;

    constexpr int M = 2 * D + 1;
    float m[M];
#pragma unroll
    for (int k = 0; k < D; ++k) { m[k] = xi[k]; m[D + k] = xj[k]; }
    m[2 * D] = ea[(size_t)b * E + e];

    float h1[8];
#pragma unroll
    for (int j = 0; j < 8; ++j) h1[j] = b1[j];
#pragma unroll
    for (int k = 0; k < M; ++k) {
        float mk = m[k];
#pragma unroll
        for (int j = 0; j < 8; ++j) h1[j] = fmaf(mk, W1[k * 8 + j], h1[j]);
    }
#pragma unroll
    for (int j = 0; j < 8; ++j) h1[j] = lrelu(h1[j]);

    float h2[8];
#pragma unroll
    for (int j = 0; j < 8; ++j) h2[j] = b2[j];
#pragma unroll
    for (int k = 0; k < 8; ++k) {
        float hk = h1[k];
#pragma unroll
        for (int j = 0; j < 8; ++j) h2[j] = fmaf(hk, W2[k * 8 + j], h2[j]);
    }

    unsigned int* ag = agg + ((size_t)b * N + d) * 8;
#pragma unroll
    for (int j = 0; j < 8; ++j) atomicMin(&ag[j], fmin_encode(h2[j]));
}

// decode agg (in place as float h), empty/inf -> 0, outer lrelu
__global__ __launch_bounds__(256) void finalize_kernel(
    unsigned int* __restrict__ agg, int total) {
    int tid = blockIdx.x * blockDim.x + threadIdx.x;
    if (tid >= total) return;
    float v = fmin_decode(agg[tid]);
    unsigned int u = __float_as_uint(v);
    if ((u & 0x7F800000u) == 0x7F800000u) v = 0.f;  // inf or NaN -> 0
    ((float*)agg)[tid] = lrelu(v);
}

// out[b] = sum_n ( x0[b,n,:]·lw[0:3] + h[b,n,:]·lw[3:11] ) + lb
__global__ __launch_bounds__(256) void pool_kernel(
    const float* __restrict__ x0, const float* __restrict__ h,
    const float* __restrict__ lw, const float* __restrict__ lb,
    float* __restrict__ out, int N) {
    int b = blockIdx.y;
    int n = blockIdx.x * blockDim.x + threadIdx.x;
    float c = 0.f;
    if (n < N) {
        const float* x = x0 + ((size_t)b * N + n) * 3;
        const float* hh = h + ((size_t)b * N + n) * 8;
        c = x[0] * lw[0] + x[1] * lw[1] + x[2] * lw[2];
#pragma unroll
        for (int k = 0; k < 8; ++k) c = fmaf(hh[k], lw[3 + k], c);
    }
#pragma unroll
    for (int off = 32; off > 0; off >>= 1) c += __shfl_down(c, off, 64);
    __shared__ float wsum[4];
    int lane = threadIdx.x & 63;
    int wave = threadIdx.x >> 6;
    if (lane == 0) wsum[wave] = c;
    __syncthreads();
    if (threadIdx.x == 0) {
        float s = wsum[0] + wsum[1] + wsum[2] + wsum[3];
        if (blockIdx.x == 0) s += lb[0];
        atomicAdd(&out[b], s);
    }
}

static inline size_t align256(size_t x) { return (x + 255) & ~(size_t)255; }

extern "C" void kernel_launch(void* const* d_in, const int* in_sizes, int n_in,
                              void* d_out, int out_size, void* d_ws, size_t ws_size,
                              hipStream_t stream) {
    const int B = 4;
    const int N = in_sizes[1] / B;            // actions [B,N]
    const int E = in_sizes[2] / (2 * B);      // edge_index [B,2,E]

    const int*   nf  = (const int*)d_in[0];
    const float* act = (const float*)d_in[1];
    const int*   ei  = (const int*)d_in[2];   // int32! (JAX x64 disabled)
    const float* ea  = (const float*)d_in[3];
    const float* c1_W1 = (const float*)d_in[4];
    const float* c1_b1 = (const float*)d_in[5];
    const float* c1_W2 = (const float*)d_in[6];
    const float* c1_b2 = (const float*)d_in[7];
    const float* c2_W1 = (const float*)d_in[8];
    const float* c2_b1 = (const float*)d_in[9];
    const float* c2_W2 = (const float*)d_in[10];
    const float* c2_b2 = (const float*)d_in[11];
    const float* c3_W1 = (const float*)d_in[12];
    const float* c3_b1 = (const float*)d_in[13];
    const float* c3_W2 = (const float*)d_in[14];
    const float* c3_b2 = (const float*)d_in[15];
    const float* lw    = (const float*)d_in[16];
    const float* lb    = (const float*)d_in[17];
    float* out = (float*)d_out;

    // ---- workspace layout (~6.1 MB) ----
    char* ws = (char*)d_ws;
    size_t off = 0;
    float* x0 = (float*)(ws + off);                 off += align256((size_t)B * N * 3 * 4);
    unsigned int* bufA = (unsigned int*)(ws + off); off += align256((size_t)B * N * 8 * 4);
    unsigned int* bufB = (unsigned int*)(ws + off); off += align256((size_t)B * N * 8 * 4);
    (void)ws_size;

    const int BN = B * N;
    const int BE = B * E;
    const int aggTotal = B * N * 8;

    hipMemsetAsync(out, 0, (size_t)B * sizeof(float), stream);

    node_init_kernel<<<(BN + 255) / 256, 256, 0, stream>>>(nf, act, x0, BN);

    const int egrid = (BE + 255) / 256;
    const int ngrid = (aggTotal + 255) / 256;
    const size_t aggBytes = (size_t)aggTotal * 4;

    // conv1 (D=3): x0 -> bufA
    hipMemsetAsync(bufA, 0xFF, aggBytes, stream);
    edge_conv_kernel<3><<<egrid, 256, 0, stream>>>(
        x0, ei, ea, c1_W1, c1_b1, c1_W2, c1_b2, bufA, E, N, B);
    finalize_kernel<<<ngrid, 256, 0, stream>>>(bufA, aggTotal);

    // conv2 (D=8): bufA -> bufB
    hipMemsetAsync(bufB, 0xFF, aggBytes, stream);
    edge_conv_kernel<8><<<egrid, 256, 0, stream>>>(
        (const float*)bufA, ei, ea, c2_W1, c2_b1, c2_W2, c2_b2, bufB, E, N, B);
    finalize_kernel<<<ngrid, 256, 0, stream>>>(bufB, aggTotal);

    // conv3 (D=8): bufB -> bufA
    hipMemsetAsync(bufA, 0xFF, aggBytes, stream);
    edge_conv_kernel<8><<<egrid, 256, 0, stream>>>(
        (const float*)bufB, ei, ea, c3_W1, c3_b1, c3_W2, c3_b2, bufA, E, N, B);
    finalize_kernel<<<ngrid, 256, 0, stream>>>(bufA, aggTotal);

    // pool + head
    dim3 pgrid((N + 255) / 256, B);
    pool_kernel<<<pgrid, 256, 0, stream>>>(x0, (const float*)bufA, lw, lb, out, N);
}

// Round 4
// 672.219 us; speedup vs baseline: 3.8268x; 3.8268x over previous
//
#include <hip/hip_runtime.h>

#define LEAK 0.01f
#define SCAN_T 256
#define SCAN_CHUNK (SCAN_T * 4)

__device__ __forceinline__ float lrelu(float v) {
    return v >= 0.f ? v : LEAK * v;
}

// ---------------------------------------------------------------------------
// common small kernels
// ---------------------------------------------------------------------------

// x0[b,n,:] = [float(nf0), float(nf1), action]
__global__ __launch_bounds__(256) void node_init_kernel(
    const int* __restrict__ nf, const float* __restrict__ act,
    float* __restrict__ x0, int BN) {
    int tid = blockIdx.x * blockDim.x + threadIdx.x;
    if (tid >= BN) return;
    x0[tid * 3 + 0] = (float)nf[tid * 2 + 0];
    x0[tid * 3 + 1] = (float)nf[tid * 2 + 1];
    x0[tid * 3 + 2] = act[tid];
}

// out[b] = sum_n ( x0[b,n,:]·lw[0:3] + h[b,n,:]·lw[3:11] ) + lb
__global__ __launch_bounds__(256) void pool_kernel(
    const float* __restrict__ x0, const float* __restrict__ h,
    const float* __restrict__ lw, const float* __restrict__ lb,
    float* __restrict__ out, int N) {
    int b = blockIdx.y;
    int n = blockIdx.x * blockDim.x + threadIdx.x;
    float c = 0.f;
    if (n < N) {
        const float* x = x0 + ((size_t)b * N + n) * 3;
        const float* hh = h + ((size_t)b * N + n) * 8;
        c = x[0] * lw[0] + x[1] * lw[1] + x[2] * lw[2];
#pragma unroll
        for (int k = 0; k < 8; ++k) c = fmaf(hh[k], lw[3 + k], c);
    }
#pragma unroll
    for (int off = 32; off > 0; off >>= 1) c += __shfl_down(c, off, 64);
    __shared__ float wsum[4];
    int lane = threadIdx.x & 63;
    int wave = threadIdx.x >> 6;
    if (lane == 0) wsum[wave] = c;
    __syncthreads();
    if (threadIdx.x == 0) {
        float s = wsum[0] + wsum[1] + wsum[2] + wsum[3];
        if (blockIdx.x == 0) s += lb[0];
        atomicAdd(&out[b], s);
    }
}

// ---------------------------------------------------------------------------
// CSR build: histogram -> exclusive scan -> scatter (edges grouped by dst)
// ---------------------------------------------------------------------------

__global__ __launch_bounds__(256) void hist_kernel(
    const int* __restrict__ ei, int* __restrict__ counts, int E, int N, int BE) {
    int tid = blockIdx.x * blockDim.x + threadIdx.x;
    if (tid >= BE) return;
    int b = tid / E;
    int e = tid - b * E;
    int d = ei[(size_t)b * 2 * E + E + e];
    atomicAdd(&counts[b * N + d], 1);
}

// block-wise exclusive scan of `in` (chunk = 1024), chunk totals -> partials
__global__ __launch_bounds__(SCAN_T) void scan_blocks_kernel(
    const int* __restrict__ in, int* __restrict__ out,
    int* __restrict__ partials, int n) {
    __shared__ int ts[SCAN_T];
    int t = threadIdx.x;
    int base = blockIdx.x * SCAN_CHUNK + t * 4;
    int v0 = 0, v1 = 0, v2 = 0, v3 = 0;
    if (base + 0 < n) v0 = in[base + 0];
    if (base + 1 < n) v1 = in[base + 1];
    if (base + 2 < n) v2 = in[base + 2];
    if (base + 3 < n) v3 = in[base + 3];
    int s = v0 + v1 + v2 + v3;
    ts[t] = s;
    __syncthreads();
    int incl = s;
    for (int off = 1; off < SCAN_T; off <<= 1) {
        int add = (t >= off) ? ts[t - off] : 0;
        __syncthreads();
        incl += add;
        ts[t] = incl;
        __syncthreads();
    }
    int excl = incl - s;
    if (base + 0 < n) out[base + 0] = excl;  excl += v0;
    if (base + 1 < n) out[base + 1] = excl;  excl += v1;
    if (base + 2 < n) out[base + 2] = excl;  excl += v2;
    if (base + 3 < n) out[base + 3] = excl;
    if (t == SCAN_T - 1) partials[blockIdx.x] = incl;
}

// exclusive scan of partials in-place (nb <= SCAN_T)
__global__ __launch_bounds__(SCAN_T) void scan_tops_kernel(
    int* __restrict__ partials, int nb) {
    __shared__ int ts[SCAN_T];
    int t = threadIdx.x;
    int s = (t < nb) ? partials[t] : 0;
    ts[t] = s;
    __syncthreads();
    int incl = s;
    for (int off = 1; off < SCAN_T; off <<= 1) {
        int add = (t >= off) ? ts[t - off] : 0;
        __syncthreads();
        incl += add;
        ts[t] = incl;
        __syncthreads();
    }
    if (t < nb) partials[t] = incl - s;
}

// add scanned partials; also init fill cursor = final rowptr
__global__ __launch_bounds__(SCAN_T) void scan_add_fill_kernel(
    int* __restrict__ out, int* __restrict__ fill,
    const int* __restrict__ partials, int n) {
    int p = partials[blockIdx.x];
    int base = blockIdx.x * SCAN_CHUNK + threadIdx.x * 4;
#pragma unroll
    for (int j = 0; j < 4; ++j) {
        int idx = base + j;
        if (idx < n) {
            int r = out[idx] + p;
            out[idx] = r;
            fill[idx] = r;
        }
    }
}

// group edges by dst: src_sorted / ea_sorted in segment order
__global__ __launch_bounds__(256) void scatter_kernel(
    const int* __restrict__ ei, const float* __restrict__ ea,
    int* __restrict__ fill, int* __restrict__ src_sorted,
    float* __restrict__ ea_sorted, int E, int N, int BE) {
    int tid = blockIdx.x * blockDim.x + threadIdx.x;
    if (tid >= BE) return;
    int b = tid / E;
    int e = tid - b * E;
    const int* eb = ei + (size_t)b * 2 * E;
    int s = eb[e];
    int d = eb[E + e];
    int pos = atomicAdd(&fill[b * N + d], 1);
    src_sorted[pos] = s;
    ea_sorted[pos] = ea[tid];  // ea is [B,E] contiguous
}

// ---------------------------------------------------------------------------
// conv layer = per-node precompute + CSR gather-min
// ---------------------------------------------------------------------------

// a1[i][j] = b1[j] + sum_k x[i][k] * W1[k][j]           (dst half, + bias)
// a2[i][j] =        sum_k x[i][k] * W1[D+k][j]          (src half)
template <int D>
__global__ __launch_bounds__(256) void precompute_kernel(
    const float* __restrict__ x, const float* __restrict__ W1,
    const float* __restrict__ b1, float* __restrict__ a1,
    float* __restrict__ a2, int BN) {
    int i = blockIdx.x * blockDim.x + threadIdx.x;
    if (i >= BN) return;
    float xi[D];
#pragma unroll
    for (int k = 0; k < D; ++k) xi[k] = x[(size_t)i * D + k];
    float v1[8], v2[8];
#pragma unroll
    for (int j = 0; j < 8; ++j) { v1[j] = b1[j]; v2[j] = 0.f; }
#pragma unroll
    for (int k = 0; k < D; ++k) {
        float xk = xi[k];
#pragma unroll
        for (int j = 0; j < 8; ++j) {
            v1[j] = fmaf(xk, W1[k * 8 + j], v1[j]);
            v2[j] = fmaf(xk, W1[(D + k) * 8 + j], v2[j]);
        }
    }
    float4* o1 = (float4*)(a1 + (size_t)i * 8);
    float4* o2 = (float4*)(a2 + (size_t)i * 8);
    o1[0] = make_float4(v1[0], v1[1], v1[2], v1[3]);
    o1[1] = make_float4(v1[4], v1[5], v1[6], v1[7]);
    o2[0] = make_float4(v2[0], v2[1], v2[2], v2[3]);
    o2[1] = make_float4(v2[4], v2[5], v2[6], v2[7]);
}

// one thread per dst node: min over its edge segment, no atomics.
// h1 = a1[dst] + a2[src] + ea * w1e ; lrelu ; h2 = b2 + W2^T h1 ; min
__global__ __launch_bounds__(256) void conv_csr_kernel(
    const float* __restrict__ a1, const float* __restrict__ a2,
    const float* __restrict__ w1e,           // W1 row 2D (8 floats)
    const float* __restrict__ W2, const float* __restrict__ b2,
    const int* __restrict__ rowptr, const int* __restrict__ counts,
    const int* __restrict__ src_sorted, const float* __restrict__ ea_sorted,
    float* __restrict__ hout, int N, int BN) {
    int i = blockIdx.x * blockDim.x + threadIdx.x;
    if (i >= BN) return;
    int b = i / N;
    size_t bN0 = (size_t)b * N;

    float we[8], bb[8];
#pragma unroll
    for (int j = 0; j < 8; ++j) { we[j] = w1e[j]; bb[j] = b2[j]; }

    const float4* a1p = (const float4*)(a1 + (size_t)i * 8);
    float4 a1lo = a1p[0], a1hi = a1p[1];
    float a1r[8] = {a1lo.x, a1lo.y, a1lo.z, a1lo.w, a1hi.x, a1hi.y, a1hi.z, a1hi.w};

    float acc[8];
#pragma unroll
    for (int j = 0; j < 8; ++j) acc[j] = __builtin_inff();

    int r0 = rowptr[i];
    int cnt = counts[i];
    for (int k = r0; k < r0 + cnt; ++k) {
        int s = src_sorted[k];
        float eav = ea_sorted[k];
        const float4* a2p = (const float4*)(a2 + (bN0 + s) * 8);
        float4 lo = a2p[0], hi = a2p[1];
        float h1[8];
        h1[0] = a1r[0] + lo.x; h1[1] = a1r[1] + lo.y;
        h1[2] = a1r[2] + lo.z; h1[3] = a1r[3] + lo.w;
        h1[4] = a1r[4] + hi.x; h1[5] = a1r[5] + hi.y;
        h1[6] = a1r[6] + hi.z; h1[7] = a1r[7] + hi.w;
#pragma unroll
        for (int j = 0; j < 8; ++j) {
            h1[j] = fmaf(eav, we[j], h1[j]);
            h1[j] = lrelu(h1[j]);
        }
        float h2[8];
#pragma unroll
        for (int j = 0; j < 8; ++j) h2[j] = bb[j];
#pragma unroll
        for (int kk = 0; kk < 8; ++kk) {
            float hk = h1[kk];
#pragma unroll
            for (int j = 0; j < 8; ++j) h2[j] = fmaf(hk, W2[kk * 8 + j], h2[j]);
        }
#pragma unroll
        for (int j = 0; j < 8; ++j) acc[j] = fminf(acc[j], h2[j]);
    }

    float o[8];
#pragma unroll
    for (int j = 0; j < 8; ++j) {
        float v = acc[j];
        unsigned int u = __float_as_uint(v);
        if ((u & 0x7F800000u) == 0x7F800000u) v = 0.f;  // inf/NaN (empty) -> 0
        o[j] = lrelu(v);
    }
    float4* op = (float4*)(hout + (size_t)i * 8);
    op[0] = make_float4(o[0], o[1], o[2], o[3]);
    op[1] = make_float4(o[4], o[5], o[6], o[7]);
}

// ---------------------------------------------------------------------------
// fallback (R3 proven path): per-edge atomic scatter-min
// ---------------------------------------------------------------------------

__device__ __forceinline__ unsigned int fmin_encode(float x) {
    unsigned int u = __float_as_uint(x);
    return (u & 0x80000000u) ? ~u : (u | 0x80000000u);
}
__device__ __forceinline__ float fmin_decode(unsigned int k) {
    unsigned int u = (k & 0x80000000u) ? (k ^ 0x80000000u) : ~k;
    return __uint_as_float(u);
}

template <int D>
__global__ __launch_bounds__(256) void edge_conv_kernel(
    const float* __restrict__ x, const int* __restrict__ ei,
    const float* __restrict__ ea,
    const float* __restrict__ W1, const float* __restrict__ b1,
    const float* __restrict__ W2, const float* __restrict__ b2,
    unsigned int* __restrict__ agg, int E, int N, int B) {
    int tid = blockIdx.x * blockDim.x + threadIdx.x;
    if (tid >= B * E) return;
    int b = tid / E;
    int e = tid - b * E;
    const int* eb = ei + (size_t)b * 2 * E;
    int s = eb[e];
    int d = eb[E + e];
    const float* xi = x + ((size_t)b * N + d) * D;
    const float* xj = x + ((size_t)b * N + s) * D;
    constexpr int M = 2 * D + 1;
    float m[M];
#pragma unroll
    for (int k = 0; k < D; ++k) { m[k] = xi[k]; m[D + k] = xj[k]; }
    m[2 * D] = ea[(size_t)b * E + e];
    float h1[8];
#pragma unroll
    for (int j = 0; j < 8; ++j) h1[j] = b1[j];
#pragma unroll
    for (int k = 0; k < M; ++k) {
        float mk = m[k];
#pragma unroll
        for (int j = 0; j < 8; ++j) h1[j] = fmaf(mk, W1[k * 8 + j], h1[j]);
    }
#pragma unroll
    for (int j = 0; j < 8; ++j) h1[j] = lrelu(h1[j]);
    float h2[8];
#pragma unroll
    for (int j = 0; j < 8; ++j) h2[j] = b2[j];
#pragma unroll
    for (int k = 0; k < 8; ++k) {
        float hk = h1[k];
#pragma unroll
        for (int j = 0; j < 8; ++j) h2[j] = fmaf(hk, W2[k * 8 + j], h2[j]);
    }
    unsigned int* ag = agg + ((size_t)b * N + d) * 8;
#pragma unroll
    for (int j = 0; j < 8; ++j) atomicMin(&ag[j], fmin_encode(h2[j]));
}

__global__ __launch_bounds__(256) void finalize_kernel(
    unsigned int* __restrict__ agg, int total) {
    int tid = blockIdx.x * blockDim.x + threadIdx.x;
    if (tid >= total) return;
    float v = fmin_decode(agg[tid]);
    unsigned int u = __float_as_uint(v);
    if ((u & 0x7F800000u) == 0x7F800000u) v = 0.f;
    ((float*)agg)[tid] = lrelu(v);
}

// ---------------------------------------------------------------------------

static inline size_t align256(size_t x) { return (x + 255) & ~(size_t)255; }

extern "C" void kernel_launch(void* const* d_in, const int* in_sizes, int n_in,
                              void* d_out, int out_size, void* d_ws, size_t ws_size,
                              hipStream_t stream) {
    const int B = 4;
    const int N = in_sizes[1] / B;            // actions [B,N]
    const int E = in_sizes[2] / (2 * B);      // edge_index [B,2,E]

    const int*   nf  = (const int*)d_in[0];
    const float* act = (const float*)d_in[1];
    const int*   ei  = (const int*)d_in[2];   // int32 (JAX x64 disabled)
    const float* ea  = (const float*)d_in[3];
    const float* c1_W1 = (const float*)d_in[4];
    const float* c1_b1 = (const float*)d_in[5];
    const float* c1_W2 = (const float*)d_in[6];
    const float* c1_b2 = (const float*)d_in[7];
    const float* c2_W1 = (const float*)d_in[8];
    const float* c2_b1 = (const float*)d_in[9];
    const float* c2_W2 = (const float*)d_in[10];
    const float* c2_b2 = (const float*)d_in[11];
    const float* c3_W1 = (const float*)d_in[12];
    const float* c3_b1 = (const float*)d_in[13];
    const float* c3_W2 = (const float*)d_in[14];
    const float* c3_b2 = (const float*)d_in[15];
    const float* lw    = (const float*)d_in[16];
    const float* lb    = (const float*)d_in[17];
    float* out = (float*)d_out;

    const int BN = B * N;
    const int BE = B * E;

    // ---- CSR-path workspace layout ----
    char* ws = (char*)d_ws;
    size_t off = 0;
    float* x0   = (float*)(ws + off);  off += align256((size_t)BN * 3 * 4);
    float* bufA = (float*)(ws + off);  off += align256((size_t)BN * 8 * 4);
    float* bufB = (float*)(ws + off);  off += align256((size_t)BN * 8 * 4);
    float* a1   = (float*)(ws + off);  off += align256((size_t)BN * 8 * 4);
    float* a2   = (float*)(ws + off);  off += align256((size_t)BN * 8 * 4);
    int* counts = (int*)(ws + off);    off += align256((size_t)BN * 4);
    int* rowptr = (int*)(ws + off);    off += align256((size_t)BN * 4);
    int* fill   = (int*)(ws + off);    off += align256((size_t)BN * 4);
    const int nScanBlocks = (BN + SCAN_CHUNK - 1) / SCAN_CHUNK;
    int* partials = (int*)(ws + off);  off += align256((size_t)nScanBlocks * 4);
    int*   src_sorted = (int*)(ws + off);   off += align256((size_t)BE * 4);
    float* ea_sorted  = (float*)(ws + off); off += align256((size_t)BE * 4);
    const bool useCSR = (off <= ws_size) && (nScanBlocks <= SCAN_T);

    hipMemsetAsync(out, 0, (size_t)B * sizeof(float), stream);
    node_init_kernel<<<(BN + 255) / 256, 256, 0, stream>>>(nf, act, x0, BN);

    const int egrid = (BE + 255) / 256;
    const int ngrid = (BN + 255) / 256;

    if (useCSR) {
        // ---- build CSR (once; shared by all 3 layers) ----
        hipMemsetAsync(counts, 0, (size_t)BN * 4, stream);
        hist_kernel<<<egrid, 256, 0, stream>>>(ei, counts, E, N, BE);
        scan_blocks_kernel<<<nScanBlocks, SCAN_T, 0, stream>>>(counts, rowptr, partials, BN);
        scan_tops_kernel<<<1, SCAN_T, 0, stream>>>(partials, nScanBlocks);
        scan_add_fill_kernel<<<nScanBlocks, SCAN_T, 0, stream>>>(rowptr, fill, partials, BN);
        scatter_kernel<<<egrid, 256, 0, stream>>>(ei, ea, fill, src_sorted, ea_sorted, E, N, BE);

        // ---- conv1 (D=3): x0 -> bufA ----
        precompute_kernel<3><<<ngrid, 256, 0, stream>>>(x0, c1_W1, c1_b1, a1, a2, BN);
        conv_csr_kernel<<<ngrid, 256, 0, stream>>>(a1, a2, c1_W1 + 6 * 8, c1_W2, c1_b2,
                                                   rowptr, counts, src_sorted, ea_sorted,
                                                   bufA, N, BN);
        // ---- conv2 (D=8): bufA -> bufB ----
        precompute_kernel<8><<<ngrid, 256, 0, stream>>>(bufA, c2_W1, c2_b1, a1, a2, BN);
        conv_csr_kernel<<<ngrid, 256, 0, stream>>>(a1, a2, c2_W1 + 16 * 8, c2_W2, c2_b2,
                                                   rowptr, counts, src_sorted, ea_sorted,
                                                   bufB, N, BN);
        // ---- conv3 (D=8): bufB -> bufA ----
        precompute_kernel<8><<<ngrid, 256, 0, stream>>>(bufB, c3_W1, c3_b1, a1, a2, BN);
        conv_csr_kernel<<<ngrid, 256, 0, stream>>>(a1, a2, c3_W1 + 16 * 8, c3_W2, c3_b2,
                                                   rowptr, counts, src_sorted, ea_sorted,
                                                   bufA, N, BN);
    } else {
        // ---- fallback: R3 proven atomic path ----
        const int aggTotal = BN * 8;
        const int agrid = (aggTotal + 255) / 256;
        const size_t aggBytes = (size_t)aggTotal * 4;
        unsigned int* uA = (unsigned int*)bufA;
        unsigned int* uB = (unsigned int*)bufB;

        hipMemsetAsync(uA, 0xFF, aggBytes, stream);
        edge_conv_kernel<3><<<egrid, 256, 0, stream>>>(
            x0, ei, ea, c1_W1, c1_b1, c1_W2, c1_b2, uA, E, N, B);
        finalize_kernel<<<agrid, 256, 0, stream>>>(uA, aggTotal);

        hipMemsetAsync(uB, 0xFF, aggBytes, stream);
        edge_conv_kernel<8><<<egrid, 256, 0, stream>>>(
            (const float*)uA, ei, ea, c2_W1, c2_b1, c2_W2, c2_b2, uB, E, N, B);
        finalize_kernel<<<agrid, 256, 0, stream>>>(uB, aggTotal);

        hipMemsetAsync(uA, 0xFF, aggBytes, stream);
        edge_conv_kernel<8><<<egrid, 256, 0, stream>>>(
            (const float*)uB, ei, ea, c3_W1, c3_b1, c3_W2, c3_b2, uA, E, N, B);
        finalize_kernel<<<agrid, 256, 0, stream>>>(uA, aggTotal);
    }

    // ---- pool + head (result is in bufA either way) ----
    dim3 pgrid((N + 255) / 256, B);
    pool_kernel<<<pgrid, 256, 0, stream>>>(x0, (const float*)bufA, lw, lb, out, N);
}

// Round 5
// 614.436 us; speedup vs baseline: 4.1867x; 1.0940x over previous
//
#include <hip/hip_runtime.h>

#define LEAK 0.01f
#define SCAN_T 256
#define SCAN_CHUNK (SCAN_T * 4)

__device__ __forceinline__ float lrelu(float v) {
    return v >= 0.f ? v : LEAK * v;
}

// ---------------------------------------------------------------------------
// common small kernels
// ---------------------------------------------------------------------------

// x0[b,n,:] = [float(nf0), float(nf1), action]
__global__ __launch_bounds__(256) void node_init_kernel(
    const int* __restrict__ nf, const float* __restrict__ act,
    float* __restrict__ x0, int BN) {
    int tid = blockIdx.x * blockDim.x + threadIdx.x;
    if (tid >= BN) return;
    x0[tid * 3 + 0] = (float)nf[tid * 2 + 0];
    x0[tid * 3 + 1] = (float)nf[tid * 2 + 1];
    x0[tid * 3 + 2] = act[tid];
}

// out[b] = sum_n ( x0[b,n,:]·lw[0:3] + h[b,n,:]·lw[3:11] ) + lb
__global__ __launch_bounds__(256) void pool_kernel(
    const float* __restrict__ x0, const float* __restrict__ h,
    const float* __restrict__ lw, const float* __restrict__ lb,
    float* __restrict__ out, int N) {
    int b = blockIdx.y;
    int n = blockIdx.x * blockDim.x + threadIdx.x;
    float c = 0.f;
    if (n < N) {
        const float* x = x0 + ((size_t)b * N + n) * 3;
        const float* hh = h + ((size_t)b * N + n) * 8;
        c = x[0] * lw[0] + x[1] * lw[1] + x[2] * lw[2];
#pragma unroll
        for (int k = 0; k < 8; ++k) c = fmaf(hh[k], lw[3 + k], c);
    }
#pragma unroll
    for (int off = 32; off > 0; off >>= 1) c += __shfl_down(c, off, 64);
    __shared__ float wsum[4];
    int lane = threadIdx.x & 63;
    int wave = threadIdx.x >> 6;
    if (lane == 0) wsum[wave] = c;
    __syncthreads();
    if (threadIdx.x == 0) {
        float s = wsum[0] + wsum[1] + wsum[2] + wsum[3];
        if (blockIdx.x == 0) s += lb[0];
        atomicAdd(&out[b], s);
    }
}

// ---------------------------------------------------------------------------
// CSR build: histogram -> exclusive scan -> scatter (edges grouped by dst)
// ---------------------------------------------------------------------------

__global__ __launch_bounds__(256) void hist_kernel(
    const int* __restrict__ ei, int* __restrict__ counts, int E, int N, int BE) {
    int tid = blockIdx.x * blockDim.x + threadIdx.x;
    if (tid >= BE) return;
    int b = tid / E;
    int e = tid - b * E;
    int d = ei[(size_t)b * 2 * E + E + e];
    atomicAdd(&counts[b * N + d], 1);
}

// block-wise exclusive scan of `in` (chunk = 1024), chunk totals -> partials
__global__ __launch_bounds__(SCAN_T) void scan_blocks_kernel(
    const int* __restrict__ in, int* __restrict__ out,
    int* __restrict__ partials, int n) {
    __shared__ int ts[SCAN_T];
    int t = threadIdx.x;
    int base = blockIdx.x * SCAN_CHUNK + t * 4;
    int v0 = 0, v1 = 0, v2 = 0, v3 = 0;
    if (base + 0 < n) v0 = in[base + 0];
    if (base + 1 < n) v1 = in[base + 1];
    if (base + 2 < n) v2 = in[base + 2];
    if (base + 3 < n) v3 = in[base + 3];
    int s = v0 + v1 + v2 + v3;
    ts[t] = s;
    __syncthreads();
    int incl = s;
    for (int off = 1; off < SCAN_T; off <<= 1) {
        int add = (t >= off) ? ts[t - off] : 0;
        __syncthreads();
        incl += add;
        ts[t] = incl;
        __syncthreads();
    }
    int excl = incl - s;
    if (base + 0 < n) out[base + 0] = excl;  excl += v0;
    if (base + 1 < n) out[base + 1] = excl;  excl += v1;
    if (base + 2 < n) out[base + 2] = excl;  excl += v2;
    if (base + 3 < n) out[base + 3] = excl;
    if (t == SCAN_T - 1) partials[blockIdx.x] = incl;
}

// exclusive scan of partials in-place (nb <= SCAN_T)
__global__ __launch_bounds__(SCAN_T) void scan_tops_kernel(
    int* __restrict__ partials, int nb) {
    __shared__ int ts[SCAN_T];
    int t = threadIdx.x;
    int s = (t < nb) ? partials[t] : 0;
    ts[t] = s;
    __syncthreads();
    int incl = s;
    for (int off = 1; off < SCAN_T; off <<= 1) {
        int add = (t >= off) ? ts[t - off] : 0;
        __syncthreads();
        incl += add;
        ts[t] = incl;
        __syncthreads();
    }
    if (t < nb) partials[t] = incl - s;
}

// add scanned partials; also init fill cursor = final rowptr
__global__ __launch_bounds__(SCAN_T) void scan_add_fill_kernel(
    int* __restrict__ out, int* __restrict__ fill,
    const int* __restrict__ partials, int n) {
    int p = partials[blockIdx.x];
    int base = blockIdx.x * SCAN_CHUNK + threadIdx.x * 4;
#pragma unroll
    for (int j = 0; j < 4; ++j) {
        int idx = base + j;
        if (idx < n) {
            int r = out[idx] + p;
            out[idx] = r;
            fill[idx] = r;
        }
    }
}

// group edges by dst: single 8B (src, ea) pair store per edge
__global__ __launch_bounds__(256) void scatter_kernel(
    const int* __restrict__ ei, const float* __restrict__ ea,
    int* __restrict__ fill, int2* __restrict__ pair_sorted,
    int E, int N, int BE) {
    int tid = blockIdx.x * blockDim.x + threadIdx.x;
    if (tid >= BE) return;
    int b = tid / E;
    int e = tid - b * E;
    const int* eb = ei + (size_t)b * 2 * E;
    int s = eb[e];
    int d = eb[E + e];
    float eav = ea[tid];  // ea is [B,E] contiguous
    int pos = atomicAdd(&fill[b * N + d], 1);
    pair_sorted[pos] = make_int2(s, __float_as_int(eav));
}

// ---------------------------------------------------------------------------
// conv layer = per-node precompute + CSR gather-min
// ---------------------------------------------------------------------------

// a1[i][j] = b1[j] + sum_k x[i][k] * W1[k][j]           (dst half, + bias)
// a2[i][j] =        sum_k x[i][k] * W1[D+k][j]          (src half)
template <int D>
__global__ __launch_bounds__(256) void precompute_kernel(
    const float* __restrict__ x, const float* __restrict__ W1,
    const float* __restrict__ b1, float* __restrict__ a1,
    float* __restrict__ a2, int BN) {
    int i = blockIdx.x * blockDim.x + threadIdx.x;
    if (i >= BN) return;
    float xi[D];
#pragma unroll
    for (int k = 0; k < D; ++k) xi[k] = x[(size_t)i * D + k];
    float v1[8], v2[8];
#pragma unroll
    for (int j = 0; j < 8; ++j) { v1[j] = b1[j]; v2[j] = 0.f; }
#pragma unroll
    for (int k = 0; k < D; ++k) {
        float xk = xi[k];
#pragma unroll
        for (int j = 0; j < 8; ++j) {
            v1[j] = fmaf(xk, W1[k * 8 + j], v1[j]);
            v2[j] = fmaf(xk, W1[(D + k) * 8 + j], v2[j]);
        }
    }
    float4* o1 = (float4*)(a1 + (size_t)i * 8);
    float4* o2 = (float4*)(a2 + (size_t)i * 8);
    o1[0] = make_float4(v1[0], v1[1], v1[2], v1[3]);
    o1[1] = make_float4(v1[4], v1[5], v1[6], v1[7]);
    o2[0] = make_float4(v2[0], v2[1], v2[2], v2[3]);
    o2[1] = make_float4(v2[4], v2[5], v2[6], v2[7]);
}

// one thread per dst node: min over its edge segment, no atomics.
// h1 = a1[dst] + a2[src] + ea * w1e ; lrelu ; h2 = b2 + W2^T h1 ; min
__global__ __launch_bounds__(256) void conv_csr_kernel(
    const float* __restrict__ a1, const float* __restrict__ a2,
    const float* __restrict__ w1e,           // W1 row 2D (8 floats)
    const float* __restrict__ W2, const float* __restrict__ b2,
    const int* __restrict__ rowptr, const int* __restrict__ counts,
    const int2* __restrict__ pair_sorted,
    float* __restrict__ hout, int N, int BN) {
    int i = blockIdx.x * blockDim.x + threadIdx.x;
    if (i >= BN) return;
    int b = i / N;
    size_t bN0 = (size_t)b * N;

    float we[8], bb[8];
#pragma unroll
    for (int j = 0; j < 8; ++j) { we[j] = w1e[j]; bb[j] = b2[j]; }

    const float4* a1p = (const float4*)(a1 + (size_t)i * 8);
    float4 a1lo = a1p[0], a1hi = a1p[1];
    float a1r[8] = {a1lo.x, a1lo.y, a1lo.z, a1lo.w, a1hi.x, a1hi.y, a1hi.z, a1hi.w};

    float acc[8];
#pragma unroll
    for (int j = 0; j < 8; ++j) acc[j] = __builtin_inff();

    int r0 = rowptr[i];
    int cnt = counts[i];
    for (int k = r0; k < r0 + cnt; ++k) {
        int2 p = pair_sorted[k];
        int s = p.x;
        float eav = __int_as_float(p.y);
        const float4* a2p = (const float4*)(a2 + (bN0 + s) * 8);
        float4 lo = a2p[0], hi = a2p[1];
        float h1[8];
        h1[0] = a1r[0] + lo.x; h1[1] = a1r[1] + lo.y;
        h1[2] = a1r[2] + lo.z; h1[3] = a1r[3] + lo.w;
        h1[4] = a1r[4] + hi.x; h1[5] = a1r[5] + hi.y;
        h1[6] = a1r[6] + hi.z; h1[7] = a1r[7] + hi.w;
#pragma unroll
        for (int j = 0; j < 8; ++j) {
            h1[j] = fmaf(eav, we[j], h1[j]);
            h1[j] = lrelu(h1[j]);
        }
        float h2[8];
#pragma unroll
        for (int j = 0; j < 8; ++j) h2[j] = bb[j];
#pragma unroll
        for (int kk = 0; kk < 8; ++kk) {
            float hk = h1[kk];
#pragma unroll
            for (int j = 0; j < 8; ++j) h2[j] = fmaf(hk, W2[kk * 8 + j], h2[j]);
        }
#pragma unroll
        for (int j = 0; j < 8; ++j) acc[j] = fminf(acc[j], h2[j]);
    }

    float o[8];
#pragma unroll
    for (int j = 0; j < 8; ++j) {
        float v = acc[j];
        unsigned int u = __float_as_uint(v);
        if ((u & 0x7F800000u) == 0x7F800000u) v = 0.f;  // inf/NaN (empty) -> 0
        o[j] = lrelu(v);
    }
    float4* op = (float4*)(hout + (size_t)i * 8);
    op[0] = make_float4(o[0], o[1], o[2], o[3]);
    op[1] = make_float4(o[4], o[5], o[6], o[7]);
}

// ---------------------------------------------------------------------------
// fallback (R3 proven path): per-edge atomic scatter-min
// ---------------------------------------------------------------------------

__device__ __forceinline__ unsigned int fmin_encode(float x) {
    unsigned int u = __float_as_uint(x);
    return (u & 0x80000000u) ? ~u : (u | 0x80000000u);
}
__device__ __forceinline__ float fmin_decode(unsigned int k) {
    unsigned int u = (k & 0x80000000u) ? (k ^ 0x80000000u) : ~k;
    return __uint_as_float(u);
}

template <int D>
__global__ __launch_bounds__(256) void edge_conv_kernel(
    const float* __restrict__ x, const int* __restrict__ ei,
    const float* __restrict__ ea,
    const float* __restrict__ W1, const float* __restrict__ b1,
    const float* __restrict__ W2, const float* __restrict__ b2,
    unsigned int* __restrict__ agg, int E, int N, int B) {
    int tid = blockIdx.x * blockDim.x + threadIdx.x;
    if (tid >= B * E) return;
    int b = tid / E;
    int e = tid - b * E;
    const int* eb = ei + (size_t)b * 2 * E;
    int s = eb[e];
    int d = eb[E + e];
    const float* xi = x + ((size_t)b * N + d) * D;
    const float* xj = x + ((size_t)b * N + s) * D;
    constexpr int M = 2 * D + 1;
    float m[M];
#pragma unroll
    for (int k = 0; k < D; ++k) { m[k] = xi[k]; m[D + k] = xj[k]; }
    m[2 * D] = ea[(size_t)b * E + e];
    float h1[8];
#pragma unroll
    for (int j = 0; j < 8; ++j) h1[j] = b1[j];
#pragma unroll
    for (int k = 0; k < M; ++k) {
        float mk = m[k];
#pragma unroll
        for (int j = 0; j < 8; ++j) h1[j] = fmaf(mk, W1[k * 8 + j], h1[j]);
    }
#pragma unroll
    for (int j = 0; j < 8; ++j) h1[j] = lrelu(h1[j]);
    float h2[8];
#pragma unroll
    for (int j = 0; j < 8; ++j) h2[j] = b2[j];
#pragma unroll
    for (int k = 0; k < 8; ++k) {
        float hk = h1[k];
#pragma unroll
        for (int j = 0; j < 8; ++j) h2[j] = fmaf(hk, W2[k * 8 + j], h2[j]);
    }
    unsigned int* ag = agg + ((size_t)b * N + d) * 8;
#pragma unroll
    for (int j = 0; j < 8; ++j) atomicMin(&ag[j], fmin_encode(h2[j]));
}

__global__ __launch_bounds__(256) void finalize_kernel(
    unsigned int* __restrict__ agg, int total) {
    int tid = blockIdx.x * blockDim.x + threadIdx.x;
    if (tid >= total) return;
    float v = fmin_decode(agg[tid]);
    unsigned int u = __float_as_uint(v);
    if ((u & 0x7F800000u) == 0x7F800000u) v = 0.f;
    ((float*)agg)[tid] = lrelu(v);
}

// ---------------------------------------------------------------------------

static inline size_t align256(size_t x) { return (x + 255) & ~(size_t)255; }

extern "C" void kernel_launch(void* const* d_in, const int* in_sizes, int n_in,
                              void* d_out, int out_size, void* d_ws, size_t ws_size,
                              hipStream_t stream) {
    const int B = 4;
    const int N = in_sizes[1] / B;            // actions [B,N]
    const int E = in_sizes[2] / (2 * B);      // edge_index [B,2,E]

    const int*   nf  = (const int*)d_in[0];
    const float* act = (const float*)d_in[1];
    const int*   ei  = (const int*)d_in[2];   // int32 (JAX x64 disabled)
    const float* ea  = (const float*)d_in[3];
    const float* c1_W1 = (const float*)d_in[4];
    const float* c1_b1 = (const float*)d_in[5];
    const float* c1_W2 = (const float*)d_in[6];
    const float* c1_b2 = (const float*)d_in[7];
    const float* c2_W1 = (const float*)d_in[8];
    const float* c2_b1 = (const float*)d_in[9];
    const float* c2_W2 = (const float*)d_in[10];
    const float* c2_b2 = (const float*)d_in[11];
    const float* c3_W1 = (const float*)d_in[12];
    const float* c3_b1 = (const float*)d_in[13];
    const float* c3_W2 = (const float*)d_in[14];
    const float* c3_b2 = (const float*)d_in[15];
    const float* lw    = (const float*)d_in[16];
    const float* lb    = (const float*)d_in[17];
    float* out = (float*)d_out;

    const int BN = B * N;
    const int BE = B * E;

    // ---- CSR-path workspace layout ----
    char* ws = (char*)d_ws;
    size_t off = 0;
    float* x0   = (float*)(ws + off);  off += align256((size_t)BN * 3 * 4);
    float* bufA = (float*)(ws + off);  off += align256((size_t)BN * 8 * 4);
    float* bufB = (float*)(ws + off);  off += align256((size_t)BN * 8 * 4);
    float* a1   = (float*)(ws + off);  off += align256((size_t)BN * 8 * 4);
    float* a2   = (float*)(ws + off);  off += align256((size_t)BN * 8 * 4);
    int* counts = (int*)(ws + off);    off += align256((size_t)BN * 4);
    int* rowptr = (int*)(ws + off);    off += align256((size_t)BN * 4);
    int* fill   = (int*)(ws + off);    off += align256((size_t)BN * 4);
    const int nScanBlocks = (BN + SCAN_CHUNK - 1) / SCAN_CHUNK;
    int* partials = (int*)(ws + off);  off += align256((size_t)nScanBlocks * 4);
    int2* pair_sorted = (int2*)(ws + off); off += align256((size_t)BE * 8);
    const bool useCSR = (off <= ws_size) && (nScanBlocks <= SCAN_T);

    hipMemsetAsync(out, 0, (size_t)B * sizeof(float), stream);
    node_init_kernel<<<(BN + 255) / 256, 256, 0, stream>>>(nf, act, x0, BN);

    const int egrid = (BE + 255) / 256;
    const int ngrid = (BN + 255) / 256;

    if (useCSR) {
        // ---- build CSR (once; shared by all 3 layers) ----
        hipMemsetAsync(counts, 0, (size_t)BN * 4, stream);
        hist_kernel<<<egrid, 256, 0, stream>>>(ei, counts, E, N, BE);
        scan_blocks_kernel<<<nScanBlocks, SCAN_T, 0, stream>>>(counts, rowptr, partials, BN);
        scan_tops_kernel<<<1, SCAN_T, 0, stream>>>(partials, nScanBlocks);
        scan_add_fill_kernel<<<nScanBlocks, SCAN_T, 0, stream>>>(rowptr, fill, partials, BN);
        scatter_kernel<<<egrid, 256, 0, stream>>>(ei, ea, fill, pair_sorted, E, N, BE);

        // ---- conv1 (D=3): x0 -> bufA ----
        precompute_kernel<3><<<ngrid, 256, 0, stream>>>(x0, c1_W1, c1_b1, a1, a2, BN);
        conv_csr_kernel<<<ngrid, 256, 0, stream>>>(a1, a2, c1_W1 + 6 * 8, c1_W2, c1_b2,
                                                   rowptr, counts, pair_sorted,
                                                   bufA, N, BN);
        // ---- conv2 (D=8): bufA -> bufB ----
        precompute_kernel<8><<<ngrid, 256, 0, stream>>>(bufA, c2_W1, c2_b1, a1, a2, BN);
        conv_csr_kernel<<<ngrid, 256, 0, stream>>>(a1, a2, c2_W1 + 16 * 8, c2_W2, c2_b2,
                                                   rowptr, counts, pair_sorted,
                                                   bufB, N, BN);
        // ---- conv3 (D=8): bufB -> bufA ----
        precompute_kernel<8><<<ngrid, 256, 0, stream>>>(bufB, c3_W1, c3_b1, a1, a2, BN);
        conv_csr_kernel<<<ngrid, 256, 0, stream>>>(a1, a2, c3_W1 + 16 * 8, c3_W2, c3_b2,
                                                   rowptr, counts, pair_sorted,
                                                   bufA, N, BN);
    } else {
        // ---- fallback: R3 proven atomic path ----
        const int aggTotal = BN * 8;
        const int agrid = (aggTotal + 255) / 256;
        const size_t aggBytes = (size_t)aggTotal * 4;
        unsigned int* uA = (unsigned int*)bufA;
        unsigned int* uB = (unsigned int*)bufB;

        hipMemsetAsync(uA, 0xFF, aggBytes, stream);
        edge_conv_kernel<3><<<egrid, 256, 0, stream>>>(
            x0, ei, ea, c1_W1, c1_b1, c1_W2, c1_b2, uA, E, N, B);
        finalize_kernel<<<agrid, 256, 0, stream>>>(uA, aggTotal);

        hipMemsetAsync(uB, 0xFF, aggBytes, stream);
        edge_conv_kernel<8><<<egrid, 256, 0, stream>>>(
            (const float*)uA, ei, ea, c2_W1, c2_b1, c2_W2, c2_b2, uB, E, N, B);
        finalize_kernel<<<agrid, 256, 0, stream>>>(uB, aggTotal);

        hipMemsetAsync(uA, 0xFF, aggBytes, stream);
        edge_conv_kernel<8><<<egrid, 256, 0, stream>>>(
            (const float*)uB, ei, ea, c3_W1, c3_b1, c3_W2, c3_b2, uA, E, N, B);
        finalize_kernel<<<agrid, 256, 0, stream>>>(uA, aggTotal);
    }

    // ---- pool + head (result is in bufA either way) ----
    dim3 pgrid((N + 255) / 256, B);
    pool_kernel<<<pgrid, 256, 0, stream>>>(x0, (const float*)bufA, lw, lb, out, N);
}

// Round 6
// 247.117 us; speedup vs baseline: 10.4098x; 2.4864x over previous
//
#include <hip/hip_runtime.h>

#define LEAK 0.01f
#define BS 128           // nodes per bucket (dl fits in 7 bits)
#define PCHUNK 8192      // edges per partition/hist block (256 thr x 32)
#define MAXTB 2048       // max total buckets supported by scan/LDS

__device__ __forceinline__ float lrelu(float v) {
    return v >= 0.f ? v : LEAK * v;
}

// ---- float <-> orderable-uint encoding for min (inf -> 0xFFFFFFFF) ----
__device__ __forceinline__ unsigned int fmin_encode(float x) {
    unsigned int u = __float_as_uint(x);
    return (u & 0x80000000u) ? ~u : (u | 0x80000000u);
}
__device__ __forceinline__ float fmin_decode(unsigned int k) {
    unsigned int u = (k & 0x80000000u) ? (k ^ 0x80000000u) : ~k;
    return __uint_as_float(u);
}

// ---------------------------------------------------------------------------
// common small kernels
// ---------------------------------------------------------------------------

__global__ __launch_bounds__(256) void node_init_kernel(
    const int* __restrict__ nf, const float* __restrict__ act,
    float* __restrict__ x0, int BN) {
    int tid = blockIdx.x * blockDim.x + threadIdx.x;
    if (tid >= BN) return;
    x0[tid * 3 + 0] = (float)nf[tid * 2 + 0];
    x0[tid * 3 + 1] = (float)nf[tid * 2 + 1];
    x0[tid * 3 + 2] = act[tid];
}

__global__ __launch_bounds__(256) void pool_kernel(
    const float* __restrict__ x0, const float* __restrict__ h,
    const float* __restrict__ lw, const float* __restrict__ lb,
    float* __restrict__ out, int N) {
    int b = blockIdx.y;
    int n = blockIdx.x * blockDim.x + threadIdx.x;
    float c = 0.f;
    if (n < N) {
        const float* x = x0 + ((size_t)b * N + n) * 3;
        const float* hh = h + ((size_t)b * N + n) * 8;
        c = x[0] * lw[0] + x[1] * lw[1] + x[2] * lw[2];
#pragma unroll
        for (int k = 0; k < 8; ++k) c = fmaf(hh[k], lw[3 + k], c);
    }
#pragma unroll
    for (int off = 32; off > 0; off >>= 1) c += __shfl_down(c, off, 64);
    __shared__ float wsum[4];
    int lane = threadIdx.x & 63;
    int wave = threadIdx.x >> 6;
    if (lane == 0) wsum[wave] = c;
    __syncthreads();
    if (threadIdx.x == 0) {
        float s = wsum[0] + wsum[1] + wsum[2] + wsum[3];
        if (blockIdx.x == 0) s += lb[0];
        atomicAdd(&out[b], s);
    }
}

// a1[i][j] = b1[j] + sum_k x[i][k]*W1[k][j]   (dst half + bias)
// a2[i][j] =        sum_k x[i][k]*W1[D+k][j]  (src half)
template <int D>
__global__ __launch_bounds__(256) void precompute_kernel(
    const float* __restrict__ x, const float* __restrict__ W1,
    const float* __restrict__ b1, float* __restrict__ a1,
    float* __restrict__ a2, int BN) {
    int i = blockIdx.x * blockDim.x + threadIdx.x;
    if (i >= BN) return;
    float xi[D];
#pragma unroll
    for (int k = 0; k < D; ++k) xi[k] = x[(size_t)i * D + k];
    float v1[8], v2[8];
#pragma unroll
    for (int j = 0; j < 8; ++j) { v1[j] = b1[j]; v2[j] = 0.f; }
#pragma unroll
    for (int k = 0; k < D; ++k) {
        float xk = xi[k];
#pragma unroll
        for (int j = 0; j < 8; ++j) {
            v1[j] = fmaf(xk, W1[k * 8 + j], v1[j]);
            v2[j] = fmaf(xk, W1[(D + k) * 8 + j], v2[j]);
        }
    }
    float4* o1 = (float4*)(a1 + (size_t)i * 8);
    float4* o2 = (float4*)(a2 + (size_t)i * 8);
    o1[0] = make_float4(v1[0], v1[1], v1[2], v1[3]);
    o1[1] = make_float4(v1[4], v1[5], v1[6], v1[7]);
    o2[0] = make_float4(v2[0], v2[1], v2[2], v2[3]);
    o2[1] = make_float4(v2[4], v2[5], v2[6], v2[7]);
}

// ---------------------------------------------------------------------------
// bucket partition: LDS-aggregated hist -> scan -> LDS-staged multisplit
// ---------------------------------------------------------------------------

__global__ __launch_bounds__(256) void bucket_hist_kernel(
    const int* __restrict__ ei, int* __restrict__ bcnt,
    int E, int NB, int TB, int BE) {
    __shared__ int lc[MAXTB];
    int t = threadIdx.x;
    for (int i = t; i < TB; i += 256) lc[i] = 0;
    __syncthreads();
    int start = blockIdx.x * PCHUNK;
    int end = min(start + PCHUNK, BE);
    for (int e = start + t; e < end; e += 256) {
        int b = e / E;
        int idx = e - b * E;
        int d = ei[(size_t)b * 2 * E + E + idx];
        atomicAdd(&lc[b * NB + (d >> 7)], 1);
    }
    __syncthreads();
    for (int i = t; i < TB; i += 256)
        if (lc[i]) atomicAdd(&bcnt[i], lc[i]);
}

// single-block exclusive scan over TB (<= 2048) elements; base[TB] = total
__global__ __launch_bounds__(1024) void bucket_scan_kernel(
    const int* __restrict__ bcnt, int* __restrict__ base,
    int* __restrict__ fill, int TB) {
    __shared__ int ts[1024];
    int t = threadIdx.x;
    int i0 = 2 * t, i1 = 2 * t + 1;
    int v0 = (i0 < TB) ? bcnt[i0] : 0;
    int v1 = (i1 < TB) ? bcnt[i1] : 0;
    int s = v0 + v1;
    ts[t] = s;
    __syncthreads();
    int incl = s;
    for (int off = 1; off < 1024; off <<= 1) {
        int add = (t >= off) ? ts[t - off] : 0;
        __syncthreads();
        incl += add;
        ts[t] = incl;
        __syncthreads();
    }
    int ex = incl - s;
    if (i0 < TB) { base[i0] = ex; fill[i0] = ex; }
    if (i1 < TB) { base[i1] = ex + v0; fill[i1] = ex + v0; }
    if (t == 0) base[TB] = ts[1023];
}

// multisplit: each block reserves one contiguous run per bucket and fills it.
// pair = { src | (d&127)<<16 , ea_bits }
__global__ __launch_bounds__(256) void part_kernel(
    const int* __restrict__ ei, const float* __restrict__ ea,
    int* __restrict__ fill, int2* __restrict__ pairs,
    int E, int NB, int TB, int BE) {
    __shared__ int lc[MAXTB];
    __shared__ int lbase[MAXTB];
    int t = threadIdx.x;
    for (int i = t; i < TB; i += 256) lc[i] = 0;
    __syncthreads();
    int start = blockIdx.x * PCHUNK;
    int pk[32];  // bucket | (local_rank << 12)
    for (int j = 0; j < 32; ++j) {
        int e = start + j * 256 + t;
        int p = -1;
        if (e < BE) {
            int b = e / E;
            int idx = e - b * E;
            int d = ei[(size_t)b * 2 * E + E + idx];
            int bkt = b * NB + (d >> 7);
            int r = atomicAdd(&lc[bkt], 1);
            p = bkt | (r << 12);
        }
        pk[j] = p;
    }
    __syncthreads();
    for (int i = t; i < TB; i += 256) {
        int c = lc[i];
        lbase[i] = c ? atomicAdd(&fill[i], c) : 0;
    }
    __syncthreads();
    for (int j = 0; j < 32; ++j) {
        int e = start + j * 256 + t;
        if (e < BE) {
            int b = e / E;
            int idx = e - b * E;
            const int* eb = ei + (size_t)b * 2 * E;
            int s = eb[idx];
            int d = eb[E + idx];
            int bkt = pk[j] & 0xFFF;
            int r = pk[j] >> 12;
            int pos = lbase[bkt] + r;
            pairs[pos] = make_int2(s | ((d & 127) << 16), __float_as_int(ea[e]));
        }
    }
}

// ---------------------------------------------------------------------------
// bucket conv: one block per 128-node bucket, LDS encoded-uint min
// ---------------------------------------------------------------------------

__global__ __launch_bounds__(256) void conv_bucket_kernel(
    const float* __restrict__ a1, const float* __restrict__ a2,
    const float* __restrict__ w1e, const float* __restrict__ W2,
    const float* __restrict__ b2, const int* __restrict__ base,
    const int2* __restrict__ pairs, float* __restrict__ hout,
    int N, int NB) {
    __shared__ float a1s[BS * 9];          // stride 9: kill stride-8 bank alias
    __shared__ unsigned int acc[BS * 9];
    int bkt = blockIdx.x;
    int b = bkt / NB;
    int n0 = (bkt - b * NB) << 7;          // first node of bucket
    int nCnt = min(BS, N - n0);
    int t = threadIdx.x;
    size_t gn0 = ((size_t)b * N + n0) * 8;

    for (int i = t; i < nCnt * 8; i += 256)
        a1s[(i >> 3) * 9 + (i & 7)] = a1[gn0 + i];
    for (int i = t; i < BS * 9; i += 256) acc[i] = 0xFFFFFFFFu;

    float we[8], bb[8];
#pragma unroll
    for (int j = 0; j < 8; ++j) { we[j] = w1e[j]; bb[j] = b2[j]; }
    __syncthreads();

    int k1 = base[bkt + 1];
    size_t a2base = (size_t)b * N * 8;
    for (int k = base[bkt] + t; k < k1; k += 256) {
        int2 p = pairs[k];
        int s = p.x & 0xFFFF;
        int dl = (p.x >> 16) & 127;
        float eav = __int_as_float(p.y);
        const float4* a2p = (const float4*)(a2 + a2base + (size_t)s * 8);
        float4 lo = a2p[0], hi = a2p[1];
        float h1[8];
        h1[0] = a1s[dl * 9 + 0] + lo.x; h1[1] = a1s[dl * 9 + 1] + lo.y;
        h1[2] = a1s[dl * 9 + 2] + lo.z; h1[3] = a1s[dl * 9 + 3] + lo.w;
        h1[4] = a1s[dl * 9 + 4] + hi.x; h1[5] = a1s[dl * 9 + 5] + hi.y;
        h1[6] = a1s[dl * 9 + 6] + hi.z; h1[7] = a1s[dl * 9 + 7] + hi.w;
#pragma unroll
        for (int j = 0; j < 8; ++j) {
            h1[j] = fmaf(eav, we[j], h1[j]);
            h1[j] = lrelu(h1[j]);
        }
        float h2[8];
#pragma unroll
        for (int j = 0; j < 8; ++j) h2[j] = bb[j];
#pragma unroll
        for (int kk = 0; kk < 8; ++kk) {
            float hk = h1[kk];
#pragma unroll
            for (int j = 0; j < 8; ++j) h2[j] = fmaf(hk, W2[kk * 8 + j], h2[j]);
        }
#pragma unroll
        for (int j = 0; j < 8; ++j)
            atomicMin(&acc[dl * 9 + j], fmin_encode(h2[j]));
    }
    __syncthreads();

    for (int i = t; i < nCnt * 8; i += 256) {
        float v = fmin_decode(acc[(i >> 3) * 9 + (i & 7)]);
        unsigned int u = __float_as_uint(v);
        if ((u & 0x7F800000u) == 0x7F800000u) v = 0.f;  // empty -> 0
        hout[gn0 + i] = lrelu(v);
    }
}

// ---------------------------------------------------------------------------
// fallback (R3 proven path): per-edge atomic scatter-min
// ---------------------------------------------------------------------------

template <int D>
__global__ __launch_bounds__(256) void edge_conv_kernel(
    const float* __restrict__ x, const int* __restrict__ ei,
    const float* __restrict__ ea,
    const float* __restrict__ W1, const float* __restrict__ b1,
    const float* __restrict__ W2, const float* __restrict__ b2,
    unsigned int* __restrict__ agg, int E, int N, int B) {
    int tid = blockIdx.x * blockDim.x + threadIdx.x;
    if (tid >= B * E) return;
    int b = tid / E;
    int e = tid - b * E;
    const int* eb = ei + (size_t)b * 2 * E;
    int s = eb[e];
    int d = eb[E + e];
    const float* xi = x + ((size_t)b * N + d) * D;
    const float* xj = x + ((size_t)b * N + s) * D;
    constexpr int M = 2 * D + 1;
    float m[M];
#pragma unroll
    for (int k = 0; k < D; ++k) { m[k] = xi[k]; m[D + k] = xj[k]; }
    m[2 * D] = ea[(size_t)b * E + e];
    float h1[8];
#pragma unroll
    for (int j = 0; j < 8; ++j) h1[j] = b1[j];
#pragma unroll
    for (int k = 0; k < M; ++k) {
        float mk = m[k];
#pragma unroll
        for (int j = 0; j < 8; ++j) h1[j] = fmaf(mk, W1[k * 8 + j], h1[j]);
    }
#pragma unroll
    for (int j = 0; j < 8; ++j) h1[j] = lrelu(h1[j]);
    float h2[8];
#pragma unroll
    for (int j = 0; j < 8; ++j) h2[j] = b2[j];
#pragma unroll
    for (int k = 0; k < 8; ++k) {
        float hk = h1[k];
#pragma unroll
        for (int j = 0; j < 8; ++j) h2[j] = fmaf(hk, W2[k * 8 + j], h2[j]);
    }
    unsigned int* ag = agg + ((size_t)b * N + d) * 8;
#pragma unroll
    for (int j = 0; j < 8; ++j) atomicMin(&ag[j], fmin_encode(h2[j]));
}

__global__ __launch_bounds__(256) void finalize_kernel(
    unsigned int* __restrict__ agg, int total) {
    int tid = blockIdx.x * blockDim.x + threadIdx.x;
    if (tid >= total) return;
    float v = fmin_decode(agg[tid]);
    unsigned int u = __float_as_uint(v);
    if ((u & 0x7F800000u) == 0x7F800000u) v = 0.f;
    ((float*)agg)[tid] = lrelu(v);
}

// ---------------------------------------------------------------------------

static inline size_t align256(size_t x) { return (x + 255) & ~(size_t)255; }

extern "C" void kernel_launch(void* const* d_in, const int* in_sizes, int n_in,
                              void* d_out, int out_size, void* d_ws, size_t ws_size,
                              hipStream_t stream) {
    const int B = 4;
    const int N = in_sizes[1] / B;            // actions [B,N]
    const int E = in_sizes[2] / (2 * B);      // edge_index [B,2,E]

    const int*   nf  = (const int*)d_in[0];
    const float* act = (const float*)d_in[1];
    const int*   ei  = (const int*)d_in[2];   // int32 (JAX x64 disabled)
    const float* ea  = (const float*)d_in[3];
    const float* c1_W1 = (const float*)d_in[4];
    const float* c1_b1 = (const float*)d_in[5];
    const float* c1_W2 = (const float*)d_in[6];
    const float* c1_b2 = (const float*)d_in[7];
    const float* c2_W1 = (const float*)d_in[8];
    const float* c2_b1 = (const float*)d_in[9];
    const float* c2_W2 = (const float*)d_in[10];
    const float* c2_b2 = (const float*)d_in[11];
    const float* c3_W1 = (const float*)d_in[12];
    const float* c3_b1 = (const float*)d_in[13];
    const float* c3_W2 = (const float*)d_in[14];
    const float* c3_b2 = (const float*)d_in[15];
    const float* lw    = (const float*)d_in[16];
    const float* lb    = (const float*)d_in[17];
    float* out = (float*)d_out;

    const int BN = B * N;
    const int BE = B * E;
    const int NB = (N + BS - 1) / BS;         // buckets per graph
    const int TB = B * NB;                    // total buckets

    // ---- workspace layout ----
    char* ws = (char*)d_ws;
    size_t off = 0;
    float* x0   = (float*)(ws + off);  off += align256((size_t)BN * 3 * 4);
    float* bufA = (float*)(ws + off);  off += align256((size_t)BN * 8 * 4);
    float* bufB = (float*)(ws + off);  off += align256((size_t)BN * 8 * 4);
    float* a1   = (float*)(ws + off);  off += align256((size_t)BN * 8 * 4);
    float* a2   = (float*)(ws + off);  off += align256((size_t)BN * 8 * 4);
    int* bcnt   = (int*)(ws + off);    off += align256((size_t)TB * 4);
    int* base   = (int*)(ws + off);    off += align256((size_t)(TB + 1) * 4);
    int* fill   = (int*)(ws + off);    off += align256((size_t)TB * 4);
    int2* pairs = (int2*)(ws + off);   off += align256((size_t)BE * 8);
    const bool useFast = (off <= ws_size) && (TB <= MAXTB) && (N <= 65536);

    hipMemsetAsync(out, 0, (size_t)B * sizeof(float), stream);
    node_init_kernel<<<(BN + 255) / 256, 256, 0, stream>>>(nf, act, x0, BN);

    const int ngrid = (BN + 255) / 256;
    const int pgrid1 = (BE + PCHUNK - 1) / PCHUNK;

    if (useFast) {
        // ---- bucket partition (once; shared by all 3 layers) ----
        hipMemsetAsync(bcnt, 0, (size_t)TB * 4, stream);
        bucket_hist_kernel<<<pgrid1, 256, 0, stream>>>(ei, bcnt, E, NB, TB, BE);
        bucket_scan_kernel<<<1, 1024, 0, stream>>>(bcnt, base, fill, TB);
        part_kernel<<<pgrid1, 256, 0, stream>>>(ei, ea, fill, pairs, E, NB, TB, BE);

        // ---- conv1 (D=3): x0 -> bufA ----
        precompute_kernel<3><<<ngrid, 256, 0, stream>>>(x0, c1_W1, c1_b1, a1, a2, BN);
        conv_bucket_kernel<<<TB, 256, 0, stream>>>(a1, a2, c1_W1 + 6 * 8, c1_W2, c1_b2,
                                                   base, pairs, bufA, N, NB);
        // ---- conv2 (D=8): bufA -> bufB ----
        precompute_kernel<8><<<ngrid, 256, 0, stream>>>(bufA, c2_W1, c2_b1, a1, a2, BN);
        conv_bucket_kernel<<<TB, 256, 0, stream>>>(a1, a2, c2_W1 + 16 * 8, c2_W2, c2_b2,
                                                   base, pairs, bufB, N, NB);
        // ---- conv3 (D=8): bufB -> bufA ----
        precompute_kernel<8><<<ngrid, 256, 0, stream>>>(bufB, c3_W1, c3_b1, a1, a2, BN);
        conv_bucket_kernel<<<TB, 256, 0, stream>>>(a1, a2, c3_W1 + 16 * 8, c3_W2, c3_b2,
                                                   base, pairs, bufA, N, NB);
    } else {
        // ---- fallback: R3 proven atomic path ----
        const int egrid = (BE + 255) / 256;
        const int aggTotal = BN * 8;
        const int agrid = (aggTotal + 255) / 256;
        const size_t aggBytes = (size_t)aggTotal * 4;
        unsigned int* uA = (unsigned int*)bufA;
        unsigned int* uB = (unsigned int*)bufB;

        hipMemsetAsync(uA, 0xFF, aggBytes, stream);
        edge_conv_kernel<3><<<egrid, 256, 0, stream>>>(
            x0, ei, ea, c1_W1, c1_b1, c1_W2, c1_b2, uA, E, N, B);
        finalize_kernel<<<agrid, 256, 0, stream>>>(uA, aggTotal);

        hipMemsetAsync(uB, 0xFF, aggBytes, stream);
        edge_conv_kernel<8><<<egrid, 256, 0, stream>>>(
            (const float*)uA, ei, ea, c2_W1, c2_b1, c2_W2, c2_b2, uB, E, N, B);
        finalize_kernel<<<agrid, 256, 0, stream>>>(uB, aggTotal);

        hipMemsetAsync(uA, 0xFF, aggBytes, stream);
        edge_conv_kernel<8><<<egrid, 256, 0, stream>>>(
            (const float*)uB, ei, ea, c3_W1, c3_b1, c3_W2, c3_b2, uA, E, N, B);
        finalize_kernel<<<agrid, 256, 0, stream>>>(uA, aggTotal);
    }

    // ---- pool + head (result is in bufA either way) ----
    dim3 pgrid((N + 255) / 256, B);
    pool_kernel<<<pgrid, 256, 0, stream>>>(x0, (const float*)bufA, lw, lb, out, N);
}

// Round 7
// 235.409 us; speedup vs baseline: 10.9275x; 1.0497x over previous
//
#include <hip/hip_runtime.h>

#define LEAK 0.01f
#define BS 128           // nodes per bucket (dl fits in 7 bits)
#define PCHUNK 2048      // edges per partition/hist block (256 thr x 8)
#define MAXNB 1024       // max buckets per graph (LDS arrays)

__device__ __forceinline__ float lrelu(float v) {
    return v >= 0.f ? v : LEAK * v;
}

// ---- float <-> orderable-uint encoding for min (inf -> 0xFFFFFFFF) ----
__device__ __forceinline__ unsigned int fmin_encode(float x) {
    unsigned int u = __float_as_uint(x);
    return (u & 0x80000000u) ? ~u : (u | 0x80000000u);
}
__device__ __forceinline__ float fmin_decode(unsigned int k) {
    unsigned int u = (k & 0x80000000u) ? (k ^ 0x80000000u) : ~k;
    return __uint_as_float(u);
}

// block-reduce (256 threads) + one atomicAdd
__device__ __forceinline__ void block_add(float c, float* dst) {
    __shared__ float wsum[4];
#pragma unroll
    for (int off = 32; off > 0; off >>= 1) c += __shfl_down(c, off, 64);
    int lane = threadIdx.x & 63;
    int wave = threadIdx.x >> 6;
    if (lane == 0) wsum[wave] = c;
    __syncthreads();
    if (threadIdx.x == 0)
        atomicAdd(dst, wsum[0] + wsum[1] + wsum[2] + wsum[3]);
}

// ---------------------------------------------------------------------------
// init + layer-1 precompute + x0 pool contribution (x0 never materialized)
// ---------------------------------------------------------------------------
__global__ __launch_bounds__(256) void init_pre1_kernel(
    const int* __restrict__ nf, const float* __restrict__ act,
    const float* __restrict__ W1, const float* __restrict__ b1,
    const float* __restrict__ lw, const float* __restrict__ lb,
    float* __restrict__ a1, float* __restrict__ a2,
    float* __restrict__ out, int N) {
    int b = blockIdx.y;
    int n = blockIdx.x * 256 + threadIdx.x;
    float c = 0.f;
    if (n < N) {
        size_t i = (size_t)b * N + n;
        float x0 = (float)nf[i * 2 + 0];
        float x1 = (float)nf[i * 2 + 1];
        float x2 = act[i];
        float v1[8], v2[8];
#pragma unroll
        for (int j = 0; j < 8; ++j) {
            v1[j] = b1[j] + x0 * W1[0 * 8 + j] + x1 * W1[1 * 8 + j] + x2 * W1[2 * 8 + j];
            v2[j] =         x0 * W1[3 * 8 + j] + x1 * W1[4 * 8 + j] + x2 * W1[5 * 8 + j];
        }
        float4* o1 = (float4*)(a1 + i * 8);
        float4* o2 = (float4*)(a2 + i * 8);
        o1[0] = make_float4(v1[0], v1[1], v1[2], v1[3]);
        o1[1] = make_float4(v1[4], v1[5], v1[6], v1[7]);
        o2[0] = make_float4(v2[0], v2[1], v2[2], v2[3]);
        o2[1] = make_float4(v2[4], v2[5], v2[6], v2[7]);
        c = x0 * lw[0] + x1 * lw[1] + x2 * lw[2];
        if (n == 0) c += lb[0];
    }
    block_add(c, &out[b]);
}

// ---------------------------------------------------------------------------
// bucket partition: LDS hist -> scan -> LDS-staged multisplit (2D grid: y=graph)
// ---------------------------------------------------------------------------

__global__ __launch_bounds__(256) void bucket_hist_kernel(
    const int* __restrict__ ei, int* __restrict__ bcnt, int E, int NB) {
    __shared__ int lc[MAXNB];
    int b = blockIdx.y;
    int t = threadIdx.x;
    for (int i = t; i < NB; i += 256) lc[i] = 0;
    __syncthreads();
    int e0 = blockIdx.x * PCHUNK;
    int end = min(e0 + PCHUNK, E);
    const int* drow = ei + (size_t)b * 2 * E + E;
    for (int e = e0 + t; e < end; e += 256)
        atomicAdd(&lc[drow[e] >> 7], 1);
    __syncthreads();
    for (int i = t; i < NB; i += 256)
        if (lc[i]) atomicAdd(&bcnt[b * NB + i], lc[i]);
}

// single-block exclusive scan over TB (<= 2048) elements; base[TB] = total
__global__ __launch_bounds__(1024) void bucket_scan_kernel(
    const int* __restrict__ bcnt, int* __restrict__ base,
    int* __restrict__ fill, int TB) {
    __shared__ int ts[1024];
    int t = threadIdx.x;
    int i0 = 2 * t, i1 = 2 * t + 1;
    int v0 = (i0 < TB) ? bcnt[i0] : 0;
    int v1 = (i1 < TB) ? bcnt[i1] : 0;
    int s = v0 + v1;
    ts[t] = s;
    __syncthreads();
    int incl = s;
    for (int off = 1; off < 1024; off <<= 1) {
        int add = (t >= off) ? ts[t - off] : 0;
        __syncthreads();
        incl += add;
        ts[t] = incl;
        __syncthreads();
    }
    int ex = incl - s;
    if (i0 < TB) { base[i0] = ex; fill[i0] = ex; }
    if (i1 < TB) { base[i1] = ex + v0; fill[i1] = ex + v0; }
    if (t == 0) base[TB] = ts[1023];
}

// multisplit: pk = bin | dl<<10 | rank<<17 ; pair = { src | dl<<16 , ea_bits }
__global__ __launch_bounds__(256) void part_kernel(
    const int* __restrict__ ei, const float* __restrict__ ea,
    int* __restrict__ fill, int2* __restrict__ pairs, int E, int NB) {
    __shared__ int lc[MAXNB];
    __shared__ int lbase[MAXNB];
    int b = blockIdx.y;
    int t = threadIdx.x;
    for (int i = t; i < NB; i += 256) lc[i] = 0;
    __syncthreads();
    int e0 = blockIdx.x * PCHUNK;
    int end = min(e0 + PCHUNK, E);
    const int* srow = ei + (size_t)b * 2 * E;
    const int* drow = srow + E;
    int pk[PCHUNK / 256];
#pragma unroll
    for (int j = 0; j < PCHUNK / 256; ++j) {
        int e = e0 + j * 256 + t;
        int p = -1;
        if (e < end) {
            int d = drow[e];
            int bin = d >> 7;
            int r = atomicAdd(&lc[bin], 1);
            p = bin | ((d & 127) << 10) | (r << 17);
        }
        pk[j] = p;
    }
    __syncthreads();
    for (int i = t; i < NB; i += 256) {
        int c = lc[i];
        lbase[i] = c ? atomicAdd(&fill[b * NB + i], c) : 0;
    }
    __syncthreads();
#pragma unroll
    for (int j = 0; j < PCHUNK / 256; ++j) {
        int e = e0 + j * 256 + t;
        if (e < end) {
            int p = pk[j];
            int bin = p & 1023;
            int dl = (p >> 10) & 127;
            int r = p >> 17;
            pairs[lbase[bin] + r] =
                make_int2(srow[e] | (dl << 16), __float_as_int(ea[(size_t)b * E + e]));
        }
    }
}

// ---------------------------------------------------------------------------
// bucket conv: one block per 128-node bucket, LDS encoded-uint min
// ---------------------------------------------------------------------------

// edge loop with 2-way ILP; results min-ed into acc[dl*9+j]
__device__ __forceinline__ void conv_edges(
    const float* __restrict__ a2g, const float* we, const float* bb,
    const float* __restrict__ W2, const int2* __restrict__ pairs,
    int k0, int k1, const float* __restrict__ a1s, unsigned int* __restrict__ acc) {
    int t = threadIdx.x;
    for (int k = k0 + t; k < k1; k += 512) {
        int2 p0 = pairs[k];
        bool has1 = (k + 256 < k1);
        int2 p1 = has1 ? pairs[k + 256] : p0;
        const float4* q0 = (const float4*)(a2g + (size_t)(p0.x & 0xFFFF) * 8);
        float4 lo0 = q0[0], hi0 = q0[1];
        const float4* q1 = (const float4*)(a2g + (size_t)(p1.x & 0xFFFF) * 8);
        float4 lo1 = q1[0], hi1 = q1[1];
#pragma unroll
        for (int which = 0; which < 2; ++which) {
            if (which == 1 && !has1) break;
            int dl = ((which ? p1.x : p0.x) >> 16) & 127;
            float eav = __int_as_float(which ? p1.y : p0.y);
            float4 lo = which ? lo1 : lo0;
            float4 hi = which ? hi1 : hi0;
            float h1[8];
            h1[0] = a1s[dl * 9 + 0] + lo.x; h1[1] = a1s[dl * 9 + 1] + lo.y;
            h1[2] = a1s[dl * 9 + 2] + lo.z; h1[3] = a1s[dl * 9 + 3] + lo.w;
            h1[4] = a1s[dl * 9 + 4] + hi.x; h1[5] = a1s[dl * 9 + 5] + hi.y;
            h1[6] = a1s[dl * 9 + 6] + hi.z; h1[7] = a1s[dl * 9 + 7] + hi.w;
#pragma unroll
            for (int j = 0; j < 8; ++j) {
                h1[j] = fmaf(eav, we[j], h1[j]);
                h1[j] = lrelu(h1[j]);
            }
            float h2[8];
#pragma unroll
            for (int j = 0; j < 8; ++j) h2[j] = bb[j];
#pragma unroll
            for (int kk = 0; kk < 8; ++kk) {
                float hk = h1[kk];
#pragma unroll
                for (int j = 0; j < 8; ++j) h2[j] = fmaf(hk, W2[kk * 8 + j], h2[j]);
            }
#pragma unroll
            for (int j = 0; j < 8; ++j)
                atomicMin(&acc[dl * 9 + j], fmin_encode(h2[j]));
        }
    }
}

// conv + next-layer precompute epilogue (h never hits HBM)
__global__ __launch_bounds__(256) void conv_mid_kernel(
    const float* __restrict__ a1, const float* __restrict__ a2,
    const float* __restrict__ w1e, const float* __restrict__ W2,
    const float* __restrict__ b2,
    const float* __restrict__ nW1, const float* __restrict__ nb1,
    const int* __restrict__ base, const int2* __restrict__ pairs,
    float* __restrict__ na1, float* __restrict__ na2, int N, int NB) {
    __shared__ float a1s[BS * 9];
    __shared__ unsigned int acc[BS * 9];
    int b = blockIdx.y;
    int bkt = b * NB + blockIdx.x;
    int n0 = blockIdx.x << 7;
    int nCnt = min(BS, N - n0);
    int t = threadIdx.x;
    size_t gn0 = ((size_t)b * N + n0) * 8;

    for (int i = t; i < nCnt * 8; i += 256)
        a1s[(i >> 3) * 9 + (i & 7)] = a1[gn0 + i];
    for (int i = t; i < BS * 9; i += 256) acc[i] = 0xFFFFFFFFu;
    float we[8], bb[8];
#pragma unroll
    for (int j = 0; j < 8; ++j) { we[j] = w1e[j]; bb[j] = b2[j]; }
    __syncthreads();

    conv_edges(a2 + (size_t)b * N * 8, we, bb, W2, pairs, base[bkt], base[bkt + 1],
               a1s, acc);
    __syncthreads();

    // decode h into a1s (reuse)
    for (int i = t; i < nCnt * 8; i += 256) {
        float v = fmin_decode(acc[(i >> 3) * 9 + (i & 7)]);
        unsigned int u = __float_as_uint(v);
        if ((u & 0x7F800000u) == 0x7F800000u) v = 0.f;
        a1s[(i >> 3) * 9 + (i & 7)] = lrelu(v);
    }
    __syncthreads();

    // next-layer precompute: 2 threads per node (half 0 -> a1', half 1 -> a2')
    int node = t >> 1, half = t & 1;
    if (node < nCnt) {
        float h[8];
#pragma unroll
        for (int j = 0; j < 8; ++j) h[j] = a1s[node * 9 + j];
        float v[8];
#pragma unroll
        for (int j = 0; j < 8; ++j) v[j] = half ? 0.f : nb1[j];
        const float* Wbase = nW1 + (half ? 64 : 0);
#pragma unroll
        for (int k = 0; k < 8; ++k) {
            float hk = h[k];
#pragma unroll
            for (int j = 0; j < 8; ++j) v[j] = fmaf(hk, Wbase[k * 8 + j], v[j]);
        }
        float* dst = (half ? na2 : na1) + gn0 + (size_t)node * 8;
        float4* o = (float4*)dst;
        o[0] = make_float4(v[0], v[1], v[2], v[3]);
        o[1] = make_float4(v[4], v[5], v[6], v[7]);
    }
}

// final conv: epilogue folds h·lw[3:11] into out[b]
__global__ __launch_bounds__(256) void conv_final_kernel(
    const float* __restrict__ a1, const float* __restrict__ a2,
    const float* __restrict__ w1e, const float* __restrict__ W2,
    const float* __restrict__ b2, const float* __restrict__ lw,
    const int* __restrict__ base, const int2* __restrict__ pairs,
    float* __restrict__ out, int N, int NB) {
    __shared__ float a1s[BS * 9];
    __shared__ unsigned int acc[BS * 9];
    int b = blockIdx.y;
    int bkt = b * NB + blockIdx.x;
    int n0 = blockIdx.x << 7;
    int nCnt = min(BS, N - n0);
    int t = threadIdx.x;
    size_t gn0 = ((size_t)b * N + n0) * 8;

    for (int i = t; i < nCnt * 8; i += 256)
        a1s[(i >> 3) * 9 + (i & 7)] = a1[gn0 + i];
    for (int i = t; i < BS * 9; i += 256) acc[i] = 0xFFFFFFFFu;
    float we[8], bb[8];
#pragma unroll
    for (int j = 0; j < 8; ++j) { we[j] = w1e[j]; bb[j] = b2[j]; }
    __syncthreads();

    conv_edges(a2 + (size_t)b * N * 8, we, bb, W2, pairs, base[bkt], base[bkt + 1],
               a1s, acc);
    __syncthreads();

    float c = 0.f;
    if (t < nCnt) {
#pragma unroll
        for (int j = 0; j < 8; ++j) {
            float v = fmin_decode(acc[t * 9 + j]);
            unsigned int u = __float_as_uint(v);
            if ((u & 0x7F800000u) == 0x7F800000u) v = 0.f;
            c = fmaf(lrelu(v), lw[3 + j], c);
        }
    }
    __syncthreads();  // protect wsum reuse inside block_add
    block_add(c, &out[b]);
}

// ---------------------------------------------------------------------------
// fallback (R3 proven path): per-edge atomic scatter-min
// ---------------------------------------------------------------------------

__global__ __launch_bounds__(256) void node_init_kernel(
    const int* __restrict__ nf, const float* __restrict__ act,
    float* __restrict__ x0, int BN) {
    int tid = blockIdx.x * blockDim.x + threadIdx.x;
    if (tid >= BN) return;
    x0[tid * 3 + 0] = (float)nf[tid * 2 + 0];
    x0[tid * 3 + 1] = (float)nf[tid * 2 + 1];
    x0[tid * 3 + 2] = act[tid];
}

template <int D>
__global__ __launch_bounds__(256) void edge_conv_kernel(
    const float* __restrict__ x, const int* __restrict__ ei,
    const float* __restrict__ ea,
    const float* __restrict__ W1, const float* __restrict__ b1,
    const float* __restrict__ W2, const float* __restrict__ b2,
    unsigned int* __restrict__ agg, int E, int N, int B) {
    int tid = blockIdx.x * blockDim.x + threadIdx.x;
    if (tid >= B * E) return;
    int b = tid / E;
    int e = tid - b * E;
    const int* eb = ei + (size_t)b * 2 * E;
    int s = eb[e];
    int d = eb[E + e];
    const float* xi = x + ((size_t)b * N + d) * D;
    const float* xj = x + ((size_t)b * N + s) * D;
    constexpr int M = 2 * D + 1;
    float m[M];
#pragma unroll
    for (int k = 0; k < D; ++k) { m[k] = xi[k]; m[D + k] = xj[k]; }
    m[2 * D] = ea[(size_t)b * E + e];
    float h1[8];
#pragma unroll
    for (int j = 0; j < 8; ++j) h1[j] = b1[j];
#pragma unroll
    for (int k = 0; k < M; ++k) {
        float mk = m[k];
#pragma unroll
        for (int j = 0; j < 8; ++j) h1[j] = fmaf(mk, W1[k * 8 + j], h1[j]);
    }
#pragma unroll
    for (int j = 0; j < 8; ++j) h1[j] = lrelu(h1[j]);
    float h2[8];
#pragma unroll
    for (int j = 0; j < 8; ++j) h2[j] = b2[j];
#pragma unroll
    for (int k = 0; k < 8; ++k) {
        float hk = h1[k];
#pragma unroll
        for (int j = 0; j < 8; ++j) h2[j] = fmaf(hk, W2[k * 8 + j], h2[j]);
    }
    unsigned int* ag = agg + ((size_t)b * N + d) * 8;
#pragma unroll
    for (int j = 0; j < 8; ++j) atomicMin(&ag[j], fmin_encode(h2[j]));
}

__global__ __launch_bounds__(256) void finalize_kernel(
    unsigned int* __restrict__ agg, int total) {
    int tid = blockIdx.x * blockDim.x + threadIdx.x;
    if (tid >= total) return;
    float v = fmin_decode(agg[tid]);
    unsigned int u = __float_as_uint(v);
    if ((u & 0x7F800000u) == 0x7F800000u) v = 0.f;
    ((float*)agg)[tid] = lrelu(v);
}

__global__ __launch_bounds__(256) void pool_kernel(
    const float* __restrict__ x0, const float* __restrict__ h,
    const float* __restrict__ lw, const float* __restrict__ lb,
    float* __restrict__ out, int N) {
    int b = blockIdx.y;
    int n = blockIdx.x * blockDim.x + threadIdx.x;
    float c = 0.f;
    if (n < N) {
        const float* x = x0 + ((size_t)b * N + n) * 3;
        const float* hh = h + ((size_t)b * N + n) * 8;
        c = x[0] * lw[0] + x[1] * lw[1] + x[2] * lw[2];
#pragma unroll
        for (int k = 0; k < 8; ++k) c = fmaf(hh[k], lw[3 + k], c);
        if (n == 0) c += lb[0];
    }
    block_add(c, &out[b]);
}

// ---------------------------------------------------------------------------

static inline size_t align256(size_t x) { return (x + 255) & ~(size_t)255; }

extern "C" void kernel_launch(void* const* d_in, const int* in_sizes, int n_in,
                              void* d_out, int out_size, void* d_ws, size_t ws_size,
                              hipStream_t stream) {
    const int B = 4;
    const int N = in_sizes[1] / B;            // actions [B,N]
    const int E = in_sizes[2] / (2 * B);      // edge_index [B,2,E]

    const int*   nf  = (const int*)d_in[0];
    const float* act = (const float*)d_in[1];
    const int*   ei  = (const int*)d_in[2];   // int32 (JAX x64 disabled)
    const float* ea  = (const float*)d_in[3];
    const float* c1_W1 = (const float*)d_in[4];
    const float* c1_b1 = (const float*)d_in[5];
    const float* c1_W2 = (const float*)d_in[6];
    const float* c1_b2 = (const float*)d_in[7];
    const float* c2_W1 = (const float*)d_in[8];
    const float* c2_b1 = (const float*)d_in[9];
    const float* c2_W2 = (const float*)d_in[10];
    const float* c2_b2 = (const float*)d_in[11];
    const float* c3_W1 = (const float*)d_in[12];
    const float* c3_b1 = (const float*)d_in[13];
    const float* c3_W2 = (const float*)d_in[14];
    const float* c3_b2 = (const float*)d_in[15];
    const float* lw    = (const float*)d_in[16];
    const float* lb    = (const float*)d_in[17];
    float* out = (float*)d_out;

    const int BN = B * N;
    const int BE = B * E;
    const int NB = (N + BS - 1) / BS;         // buckets per graph
    const int TB = B * NB;                    // total buckets
    const int CPG = (E + PCHUNK - 1) / PCHUNK;

    // ---- workspace layout ----
    char* ws = (char*)d_ws;
    size_t off = 0;
    float* a1A  = (float*)(ws + off);  off += align256((size_t)BN * 8 * 4);
    float* a2A  = (float*)(ws + off);  off += align256((size_t)BN * 8 * 4);
    float* a1B  = (float*)(ws + off);  off += align256((size_t)BN * 8 * 4);
    float* a2B  = (float*)(ws + off);  off += align256((size_t)BN * 8 * 4);
    int* bcnt   = (int*)(ws + off);    off += align256((size_t)TB * 4);
    int* base   = (int*)(ws + off);    off += align256((size_t)(TB + 1) * 4);
    int* fill   = (int*)(ws + off);    off += align256((size_t)TB * 4);
    int2* pairs = (int2*)(ws + off);   off += align256((size_t)BE * 8);
    // fallback extras
    float* x0   = (float*)(ws + off);  off += align256((size_t)BN * 3 * 4);
    const bool useFast = (off <= ws_size) && (NB <= MAXNB) && (TB <= 2048) &&
                         (N <= 65536);

    hipMemsetAsync(out, 0, (size_t)B * sizeof(float), stream);

    if (useFast) {
        dim3 egrid(CPG, B);
        dim3 igrid((N + 255) / 256, B);
        dim3 cgrid(NB, B);

        hipMemsetAsync(bcnt, 0, (size_t)TB * 4, stream);
        init_pre1_kernel<<<igrid, 256, 0, stream>>>(nf, act, c1_W1, c1_b1,
                                                    lw, lb, a1A, a2A, out, N);
        bucket_hist_kernel<<<egrid, 256, 0, stream>>>(ei, bcnt, E, NB);
        bucket_scan_kernel<<<1, 1024, 0, stream>>>(bcnt, base, fill, TB);
        part_kernel<<<egrid, 256, 0, stream>>>(ei, ea, fill, pairs, E, NB);

        // conv1: a1A/a2A -> (epilogue pre2) a1B/a2B
        conv_mid_kernel<<<cgrid, 256, 0, stream>>>(
            a1A, a2A, c1_W1 + 6 * 8, c1_W2, c1_b2, c2_W1, c2_b1,
            base, pairs, a1B, a2B, N, NB);
        // conv2: a1B/a2B -> (epilogue pre3) a1A/a2A
        conv_mid_kernel<<<cgrid, 256, 0, stream>>>(
            a1B, a2B, c2_W1 + 16 * 8, c2_W2, c2_b2, c3_W1, c3_b1,
            base, pairs, a1A, a2A, N, NB);
        // conv3: a1A/a2A -> out (pool fold)
        conv_final_kernel<<<cgrid, 256, 0, stream>>>(
            a1A, a2A, c3_W1 + 16 * 8, c3_W2, c3_b2, lw,
            base, pairs, out, N, NB);
    } else {
        // ---- fallback: R3 proven atomic path ----
        const int egrid = (BE + 255) / 256;
        const int aggTotal = BN * 8;
        const int agrid = (aggTotal + 255) / 256;
        const size_t aggBytes = (size_t)aggTotal * 4;
        unsigned int* uA = (unsigned int*)a1A;
        unsigned int* uB = (unsigned int*)a1B;

        node_init_kernel<<<(BN + 255) / 256, 256, 0, stream>>>(nf, act, x0, BN);

        hipMemsetAsync(uA, 0xFF, aggBytes, stream);
        edge_conv_kernel<3><<<egrid, 256, 0, stream>>>(
            x0, ei, ea, c1_W1, c1_b1, c1_W2, c1_b2, uA, E, N, B);
        finalize_kernel<<<agrid, 256, 0, stream>>>(uA, aggTotal);

        hipMemsetAsync(uB, 0xFF, aggBytes, stream);
        edge_conv_kernel<8><<<egrid, 256, 0, stream>>>(
            (const float*)uA, ei, ea, c2_W1, c2_b1, c2_W2, c2_b2, uB, E, N, B);
        finalize_kernel<<<agrid, 256, 0, stream>>>(uB, aggTotal);

        hipMemsetAsync(uA, 0xFF, aggBytes, stream);
        edge_conv_kernel<8><<<egrid, 256, 0, stream>>>(
            (const float*)uB, ei, ea, c3_W1, c3_b1, c3_W2, c3_b2, uA, E, N, B);
        finalize_kernel<<<agrid, 256, 0, stream>>>(uA, aggTotal);

        dim3 pgrid((N + 255) / 256, B);
        pool_kernel<<<pgrid, 256, 0, stream>>>(x0, (const float*)uA, lw, lb, out, N);
    }
}

// Round 8
// 223.833 us; speedup vs baseline: 11.4927x; 1.0517x over previous
//
#include <hip/hip_runtime.h>

#define LEAK 0.01f
#define BS 128           // nodes per bucket (dl fits in 7 bits)
#define PCHUNK 8192      // edges per partition/hist block (long runs => full sectors)
#define PT 512           // threads for part/hist (8 waves: latency hiding)
#define CT 512           // threads for conv kernels
#define MAXNB 1024       // max buckets per graph (LDS arrays)

__device__ __forceinline__ float lrelu(float v) {
    return v >= 0.f ? v : LEAK * v;
}

// ---- float <-> orderable-uint encoding for min (inf -> 0xFFFFFFFF) ----
__device__ __forceinline__ unsigned int fmin_encode(float x) {
    unsigned int u = __float_as_uint(x);
    return (u & 0x80000000u) ? ~u : (u | 0x80000000u);
}
__device__ __forceinline__ float fmin_decode(unsigned int k) {
    unsigned int u = (k & 0x80000000u) ? (k ^ 0x80000000u) : ~k;
    return __uint_as_float(u);
}

// block-reduce (any multiple-of-64 block) + one atomicAdd
__device__ __forceinline__ void block_add(float c, float* dst) {
    __shared__ float wsum[8];
#pragma unroll
    for (int off = 32; off > 0; off >>= 1) c += __shfl_down(c, off, 64);
    int lane = threadIdx.x & 63;
    int wave = threadIdx.x >> 6;
    if (lane == 0) wsum[wave] = c;
    __syncthreads();
    if (threadIdx.x == 0) {
        float s = 0.f;
        int nw = blockDim.x >> 6;
        for (int w = 0; w < nw; ++w) s += wsum[w];
        atomicAdd(dst, s);
    }
}

// ---------------------------------------------------------------------------
// init + layer-1 precompute + x0 pool contribution (x0 never materialized)
// ---------------------------------------------------------------------------
__global__ __launch_bounds__(256) void init_pre1_kernel(
    const int* __restrict__ nf, const float* __restrict__ act,
    const float* __restrict__ W1, const float* __restrict__ b1,
    const float* __restrict__ lw, const float* __restrict__ lb,
    float* __restrict__ a1, float* __restrict__ a2,
    float* __restrict__ out, int N) {
    int b = blockIdx.y;
    int n = blockIdx.x * 256 + threadIdx.x;
    float c = 0.f;
    if (n < N) {
        size_t i = (size_t)b * N + n;
        float x0 = (float)nf[i * 2 + 0];
        float x1 = (float)nf[i * 2 + 1];
        float x2 = act[i];
        float v1[8], v2[8];
#pragma unroll
        for (int j = 0; j < 8; ++j) {
            v1[j] = b1[j] + x0 * W1[0 * 8 + j] + x1 * W1[1 * 8 + j] + x2 * W1[2 * 8 + j];
            v2[j] =         x0 * W1[3 * 8 + j] + x1 * W1[4 * 8 + j] + x2 * W1[5 * 8 + j];
        }
        float4* o1 = (float4*)(a1 + i * 8);
        float4* o2 = (float4*)(a2 + i * 8);
        o1[0] = make_float4(v1[0], v1[1], v1[2], v1[3]);
        o1[1] = make_float4(v1[4], v1[5], v1[6], v1[7]);
        o2[0] = make_float4(v2[0], v2[1], v2[2], v2[3]);
        o2[1] = make_float4(v2[4], v2[5], v2[6], v2[7]);
        c = x0 * lw[0] + x1 * lw[1] + x2 * lw[2];
        if (n == 0) c += lb[0];
    }
    block_add(c, &out[b]);
}

// ---------------------------------------------------------------------------
// bucket partition: LDS hist -> scan -> LDS-staged multisplit (2D grid: y=graph)
// ---------------------------------------------------------------------------

__global__ __launch_bounds__(PT) void bucket_hist_kernel(
    const int* __restrict__ ei, int* __restrict__ bcnt, int E, int NB) {
    __shared__ int lc[MAXNB];
    int b = blockIdx.y;
    int t = threadIdx.x;
    for (int i = t; i < NB; i += PT) lc[i] = 0;
    __syncthreads();
    int e0 = blockIdx.x * PCHUNK;
    int end = min(e0 + PCHUNK, E);
    const int* drow = ei + (size_t)b * 2 * E + E;
    for (int e = e0 + t; e < end; e += PT)
        atomicAdd(&lc[drow[e] >> 7], 1);
    __syncthreads();
    for (int i = t; i < NB; i += PT)
        if (lc[i]) atomicAdd(&bcnt[b * NB + i], lc[i]);
}

// single-block exclusive scan over TB (<= 2048) elements; base[TB] = total
__global__ __launch_bounds__(1024) void bucket_scan_kernel(
    const int* __restrict__ bcnt, int* __restrict__ base,
    int* __restrict__ fill, int TB) {
    __shared__ int ts[1024];
    int t = threadIdx.x;
    int i0 = 2 * t, i1 = 2 * t + 1;
    int v0 = (i0 < TB) ? bcnt[i0] : 0;
    int v1 = (i1 < TB) ? bcnt[i1] : 0;
    int s = v0 + v1;
    ts[t] = s;
    __syncthreads();
    int incl = s;
    for (int off = 1; off < 1024; off <<= 1) {
        int add = (t >= off) ? ts[t - off] : 0;
        __syncthreads();
        incl += add;
        ts[t] = incl;
        __syncthreads();
    }
    int ex = incl - s;
    if (i0 < TB) { base[i0] = ex; fill[i0] = ex; }
    if (i1 < TB) { base[i1] = ex + v0; fill[i1] = ex + v0; }
    if (t == 0) base[TB] = ts[1023];
}

// multisplit: pk = bin | dl<<10 | rank<<17 ; pair = { src | dl<<16 , ea_bits }
__global__ __launch_bounds__(PT) void part_kernel(
    const int* __restrict__ ei, const float* __restrict__ ea,
    int* __restrict__ fill, int2* __restrict__ pairs, int E, int NB) {
    __shared__ int lc[MAXNB];
    __shared__ int lbase[MAXNB];
    int b = blockIdx.y;
    int t = threadIdx.x;
    for (int i = t; i < NB; i += PT) lc[i] = 0;
    __syncthreads();
    int e0 = blockIdx.x * PCHUNK;
    int end = min(e0 + PCHUNK, E);
    const int* srow = ei + (size_t)b * 2 * E;
    const int* drow = srow + E;
    int pk[PCHUNK / PT];
#pragma unroll
    for (int j = 0; j < PCHUNK / PT; ++j) {
        int e = e0 + j * PT + t;
        int p = -1;
        if (e < end) {
            int d = drow[e];
            int bin = d >> 7;
            int r = atomicAdd(&lc[bin], 1);
            p = bin | ((d & 127) << 10) | (r << 17);
        }
        pk[j] = p;
    }
    __syncthreads();
    for (int i = t; i < NB; i += PT) {
        int c = lc[i];
        lbase[i] = c ? atomicAdd(&fill[b * NB + i], c) : 0;
    }
    __syncthreads();
#pragma unroll
    for (int j = 0; j < PCHUNK / PT; ++j) {
        int e = e0 + j * PT + t;
        if (e < end) {
            int p = pk[j];
            int bin = p & 1023;
            int dl = (p >> 10) & 127;
            int r = p >> 17;
            pairs[lbase[bin] + r] =
                make_int2(srow[e] | (dl << 16), __float_as_int(ea[(size_t)b * E + e]));
        }
    }
}

// ---------------------------------------------------------------------------
// bucket conv: one block per 128-node bucket, LDS encoded-uint min
// ---------------------------------------------------------------------------

// edge loop with 2-way ILP; results min-ed into acc[dl*9+j]
__device__ __forceinline__ void conv_edges(
    const float* __restrict__ a2g, const float* we, const float* bb,
    const float* __restrict__ W2, const int2* __restrict__ pairs,
    int k0, int k1, const float* __restrict__ a1s, unsigned int* __restrict__ acc) {
    int t = threadIdx.x;
    for (int k = k0 + t; k < k1; k += 2 * CT) {
        int2 p0 = pairs[k];
        bool has1 = (k + CT < k1);
        int2 p1 = has1 ? pairs[k + CT] : p0;
        const float4* q0 = (const float4*)(a2g + (size_t)(p0.x & 0xFFFF) * 8);
        float4 lo0 = q0[0], hi0 = q0[1];
        const float4* q1 = (const float4*)(a2g + (size_t)(p1.x & 0xFFFF) * 8);
        float4 lo1 = q1[0], hi1 = q1[1];
#pragma unroll
        for (int which = 0; which < 2; ++which) {
            if (which == 1 && !has1) break;
            int dl = ((which ? p1.x : p0.x) >> 16) & 127;
            float eav = __int_as_float(which ? p1.y : p0.y);
            float4 lo = which ? lo1 : lo0;
            float4 hi = which ? hi1 : hi0;
            float h1[8];
            h1[0] = a1s[dl * 9 + 0] + lo.x; h1[1] = a1s[dl * 9 + 1] + lo.y;
            h1[2] = a1s[dl * 9 + 2] + lo.z; h1[3] = a1s[dl * 9 + 3] + lo.w;
            h1[4] = a1s[dl * 9 + 4] + hi.x; h1[5] = a1s[dl * 9 + 5] + hi.y;
            h1[6] = a1s[dl * 9 + 6] + hi.z; h1[7] = a1s[dl * 9 + 7] + hi.w;
#pragma unroll
            for (int j = 0; j < 8; ++j) {
                h1[j] = fmaf(eav, we[j], h1[j]);
                h1[j] = lrelu(h1[j]);
            }
            float h2[8];
#pragma unroll
            for (int j = 0; j < 8; ++j) h2[j] = bb[j];
#pragma unroll
            for (int kk = 0; kk < 8; ++kk) {
                float hk = h1[kk];
#pragma unroll
                for (int j = 0; j < 8; ++j) h2[j] = fmaf(hk, W2[kk * 8 + j], h2[j]);
            }
#pragma unroll
            for (int j = 0; j < 8; ++j)
                atomicMin(&acc[dl * 9 + j], fmin_encode(h2[j]));
        }
    }
}

// conv + next-layer precompute epilogue (h never hits HBM)
__global__ __launch_bounds__(CT) void conv_mid_kernel(
    const float* __restrict__ a1, const float* __restrict__ a2,
    const float* __restrict__ w1e, const float* __restrict__ W2,
    const float* __restrict__ b2,
    const float* __restrict__ nW1, const float* __restrict__ nb1,
    const int* __restrict__ base, const int2* __restrict__ pairs,
    float* __restrict__ na1, float* __restrict__ na2, int N, int NB) {
    __shared__ float a1s[BS * 9];
    __shared__ unsigned int acc[BS * 9];
    int b = blockIdx.y;
    int bkt = b * NB + blockIdx.x;
    int n0 = blockIdx.x << 7;
    int nCnt = min(BS, N - n0);
    int t = threadIdx.x;
    size_t gn0 = ((size_t)b * N + n0) * 8;

    for (int i = t; i < nCnt * 8; i += CT)
        a1s[(i >> 3) * 9 + (i & 7)] = a1[gn0 + i];
    for (int i = t; i < BS * 9; i += CT) acc[i] = 0xFFFFFFFFu;
    float we[8], bb[8];
#pragma unroll
    for (int j = 0; j < 8; ++j) { we[j] = w1e[j]; bb[j] = b2[j]; }
    __syncthreads();

    conv_edges(a2 + (size_t)b * N * 8, we, bb, W2, pairs, base[bkt], base[bkt + 1],
               a1s, acc);
    __syncthreads();

    // decode h into a1s (reuse)
    for (int i = t; i < nCnt * 8; i += CT) {
        float v = fmin_decode(acc[(i >> 3) * 9 + (i & 7)]);
        unsigned int u = __float_as_uint(v);
        if ((u & 0x7F800000u) == 0x7F800000u) v = 0.f;
        a1s[(i >> 3) * 9 + (i & 7)] = lrelu(v);
    }
    __syncthreads();

    // next-layer precompute: 2 threads per node (half 0 -> a1', half 1 -> a2')
    int node = t >> 1, half = t & 1;
    if (node < nCnt) {
        float h[8];
#pragma unroll
        for (int j = 0; j < 8; ++j) h[j] = a1s[node * 9 + j];
        float v[8];
#pragma unroll
        for (int j = 0; j < 8; ++j) v[j] = half ? 0.f : nb1[j];
        const float* Wbase = nW1 + (half ? 64 : 0);
#pragma unroll
        for (int k = 0; k < 8; ++k) {
            float hk = h[k];
#pragma unroll
            for (int j = 0; j < 8; ++j) v[j] = fmaf(hk, Wbase[k * 8 + j], v[j]);
        }
        float* dst = (half ? na2 : na1) + gn0 + (size_t)node * 8;
        float4* o = (float4*)dst;
        o[0] = make_float4(v[0], v[1], v[2], v[3]);
        o[1] = make_float4(v[4], v[5], v[6], v[7]);
    }
}

// final conv: epilogue folds h·lw[3:11] into out[b]
__global__ __launch_bounds__(CT) void conv_final_kernel(
    const float* __restrict__ a1, const float* __restrict__ a2,
    const float* __restrict__ w1e, const float* __restrict__ W2,
    const float* __restrict__ b2, const float* __restrict__ lw,
    const int* __restrict__ base, const int2* __restrict__ pairs,
    float* __restrict__ out, int N, int NB) {
    __shared__ float a1s[BS * 9];
    __shared__ unsigned int acc[BS * 9];
    int b = blockIdx.y;
    int bkt = b * NB + blockIdx.x;
    int n0 = blockIdx.x << 7;
    int nCnt = min(BS, N - n0);
    int t = threadIdx.x;
    size_t gn0 = ((size_t)b * N + n0) * 8;

    for (int i = t; i < nCnt * 8; i += CT)
        a1s[(i >> 3) * 9 + (i & 7)] = a1[gn0 + i];
    for (int i = t; i < BS * 9; i += CT) acc[i] = 0xFFFFFFFFu;
    float we[8], bb[8];
#pragma unroll
    for (int j = 0; j < 8; ++j) { we[j] = w1e[j]; bb[j] = b2[j]; }
    __syncthreads();

    conv_edges(a2 + (size_t)b * N * 8, we, bb, W2, pairs, base[bkt], base[bkt + 1],
               a1s, acc);
    __syncthreads();

    float c = 0.f;
    if (t < nCnt) {
#pragma unroll
        for (int j = 0; j < 8; ++j) {
            float v = fmin_decode(acc[t * 9 + j]);
            unsigned int u = __float_as_uint(v);
            if ((u & 0x7F800000u) == 0x7F800000u) v = 0.f;
            c = fmaf(lrelu(v), lw[3 + j], c);
        }
    }
    __syncthreads();
    block_add(c, &out[b]);
}

// ---------------------------------------------------------------------------
// fallback (R3 proven path): per-edge atomic scatter-min
// ---------------------------------------------------------------------------

__global__ __launch_bounds__(256) void node_init_kernel(
    const int* __restrict__ nf, const float* __restrict__ act,
    float* __restrict__ x0, int BN) {
    int tid = blockIdx.x * blockDim.x + threadIdx.x;
    if (tid >= BN) return;
    x0[tid * 3 + 0] = (float)nf[tid * 2 + 0];
    x0[tid * 3 + 1] = (float)nf[tid * 2 + 1];
    x0[tid * 3 + 2] = act[tid];
}

template <int D>
__global__ __launch_bounds__(256) void edge_conv_kernel(
    const float* __restrict__ x, const int* __restrict__ ei,
    const float* __restrict__ ea,
    const float* __restrict__ W1, const float* __restrict__ b1,
    const float* __restrict__ W2, const float* __restrict__ b2,
    unsigned int* __restrict__ agg, int E, int N, int B) {
    int tid = blockIdx.x * blockDim.x + threadIdx.x;
    if (tid >= B * E) return;
    int b = tid / E;
    int e = tid - b * E;
    const int* eb = ei + (size_t)b * 2 * E;
    int s = eb[e];
    int d = eb[E + e];
    const float* xi = x + ((size_t)b * N + d) * D;
    const float* xj = x + ((size_t)b * N + s) * D;
    constexpr int M = 2 * D + 1;
    float m[M];
#pragma unroll
    for (int k = 0; k < D; ++k) { m[k] = xi[k]; m[D + k] = xj[k]; }
    m[2 * D] = ea[(size_t)b * E + e];
    float h1[8];
#pragma unroll
    for (int j = 0; j < 8; ++j) h1[j] = b1[j];
#pragma unroll
    for (int k = 0; k < M; ++k) {
        float mk = m[k];
#pragma unroll
        for (int j = 0; j < 8; ++j) h1[j] = fmaf(mk, W1[k * 8 + j], h1[j]);
    }
#pragma unroll
    for (int j = 0; j < 8; ++j) h1[j] = lrelu(h1[j]);
    float h2[8];
#pragma unroll
    for (int j = 0; j < 8; ++j) h2[j] = b2[j];
#pragma unroll
    for (int k = 0; k < 8; ++k) {
        float hk = h1[k];
#pragma unroll
        for (int j = 0; j < 8; ++j) h2[j] = fmaf(hk, W2[k * 8 + j], h2[j]);
    }
    unsigned int* ag = agg + ((size_t)b * N + d) * 8;
#pragma unroll
    for (int j = 0; j < 8; ++j) atomicMin(&ag[j], fmin_encode(h2[j]));
}

__global__ __launch_bounds__(256) void finalize_kernel(
    unsigned int* __restrict__ agg, int total) {
    int tid = blockIdx.x * blockDim.x + threadIdx.x;
    if (tid >= total) return;
    float v = fmin_decode(agg[tid]);
    unsigned int u = __float_as_uint(v);
    if ((u & 0x7F800000u) == 0x7F800000u) v = 0.f;
    ((float*)agg)[tid] = lrelu(v);
}

__global__ __launch_bounds__(256) void pool_kernel(
    const float* __restrict__ x0, const float* __restrict__ h,
    const float* __restrict__ lw, const float* __restrict__ lb,
    float* __restrict__ out, int N) {
    int b = blockIdx.y;
    int n = blockIdx.x * blockDim.x + threadIdx.x;
    float c = 0.f;
    if (n < N) {
        const float* x = x0 + ((size_t)b * N + n) * 3;
        const float* hh = h + ((size_t)b * N + n) * 8;
        c = x[0] * lw[0] + x[1] * lw[1] + x[2] * lw[2];
#pragma unroll
        for (int k = 0; k < 8; ++k) c = fmaf(hh[k], lw[3 + k], c);
        if (n == 0) c += lb[0];
    }
    block_add(c, &out[b]);
}

// ---------------------------------------------------------------------------

static inline size_t align256(size_t x) { return (x + 255) & ~(size_t)255; }

extern "C" void kernel_launch(void* const* d_in, const int* in_sizes, int n_in,
                              void* d_out, int out_size, void* d_ws, size_t ws_size,
                              hipStream_t stream) {
    const int B = 4;
    const int N = in_sizes[1] / B;            // actions [B,N]
    const int E = in_sizes[2] / (2 * B);      // edge_index [B,2,E]

    const int*   nf  = (const int*)d_in[0];
    const float* act = (const float*)d_in[1];
    const int*   ei  = (const int*)d_in[2];   // int32 (JAX x64 disabled)
    const float* ea  = (const float*)d_in[3];
    const float* c1_W1 = (const float*)d_in[4];
    const float* c1_b1 = (const float*)d_in[5];
    const float* c1_W2 = (const float*)d_in[6];
    const float* c1_b2 = (const float*)d_in[7];
    const float* c2_W1 = (const float*)d_in[8];
    const float* c2_b1 = (const float*)d_in[9];
    const float* c2_W2 = (const float*)d_in[10];
    const float* c2_b2 = (const float*)d_in[11];
    const float* c3_W1 = (const float*)d_in[12];
    const float* c3_b1 = (const float*)d_in[13];
    const float* c3_W2 = (const float*)d_in[14];
    const float* c3_b2 = (const float*)d_in[15];
    const float* lw    = (const float*)d_in[16];
    const float* lb    = (const float*)d_in[17];
    float* out = (float*)d_out;

    const int BN = B * N;
    const int BE = B * E;
    const int NB = (N + BS - 1) / BS;         // buckets per graph
    const int TB = B * NB;                    // total buckets
    const int CPG = (E + PCHUNK - 1) / PCHUNK;

    // ---- workspace layout ----
    char* ws = (char*)d_ws;
    size_t off = 0;
    float* a1A  = (float*)(ws + off);  off += align256((size_t)BN * 8 * 4);
    float* a2A  = (float*)(ws + off);  off += align256((size_t)BN * 8 * 4);
    float* a1B  = (float*)(ws + off);  off += align256((size_t)BN * 8 * 4);
    float* a2B  = (float*)(ws + off);  off += align256((size_t)BN * 8 * 4);
    int* bcnt   = (int*)(ws + off);    off += align256((size_t)TB * 4);
    int* base   = (int*)(ws + off);    off += align256((size_t)(TB + 1) * 4);
    int* fill   = (int*)(ws + off);    off += align256((size_t)TB * 4);
    int2* pairs = (int2*)(ws + off);   off += align256((size_t)BE * 8);
    // fallback extras
    float* x0   = (float*)(ws + off);  off += align256((size_t)BN * 3 * 4);
    const bool useFast = (off <= ws_size) && (NB <= MAXNB) && (TB <= 2048) &&
                         (N <= 65536);

    hipMemsetAsync(out, 0, (size_t)B * sizeof(float), stream);

    if (useFast) {
        dim3 egrid(CPG, B);
        dim3 igrid((N + 255) / 256, B);
        dim3 cgrid(NB, B);

        hipMemsetAsync(bcnt, 0, (size_t)TB * 4, stream);
        init_pre1_kernel<<<igrid, 256, 0, stream>>>(nf, act, c1_W1, c1_b1,
                                                    lw, lb, a1A, a2A, out, N);
        bucket_hist_kernel<<<egrid, PT, 0, stream>>>(ei, bcnt, E, NB);
        bucket_scan_kernel<<<1, 1024, 0, stream>>>(bcnt, base, fill, TB);
        part_kernel<<<egrid, PT, 0, stream>>>(ei, ea, fill, pairs, E, NB);

        // conv1: a1A/a2A -> (epilogue pre2) a1B/a2B
        conv_mid_kernel<<<cgrid, CT, 0, stream>>>(
            a1A, a2A, c1_W1 + 6 * 8, c1_W2, c1_b2, c2_W1, c2_b1,
            base, pairs, a1B, a2B, N, NB);
        // conv2: a1B/a2B -> (epilogue pre3) a1A/a2A
        conv_mid_kernel<<<cgrid, CT, 0, stream>>>(
            a1B, a2B, c2_W1 + 16 * 8, c2_W2, c2_b2, c3_W1, c3_b1,
            base, pairs, a1A, a2A, N, NB);
        // conv3: a1A/a2A -> out (pool fold)
        conv_final_kernel<<<cgrid, CT, 0, stream>>>(
            a1A, a2A, c3_W1 + 16 * 8, c3_W2, c3_b2, lw,
            base, pairs, out, N, NB);
    } else {
        // ---- fallback: R3 proven atomic path ----
        const int egrid = (BE + 255) / 256;
        const int aggTotal = BN * 8;
        const int agrid = (aggTotal + 255) / 256;
        const size_t aggBytes = (size_t)aggTotal * 4;
        unsigned int* uA = (unsigned int*)a1A;
        unsigned int* uB = (unsigned int*)a1B;

        node_init_kernel<<<(BN + 255) / 256, 256, 0, stream>>>(nf, act, x0, BN);

        hipMemsetAsync(uA, 0xFF, aggBytes, stream);
        edge_conv_kernel<3><<<egrid, 256, 0, stream>>>(
            x0, ei, ea, c1_W1, c1_b1, c1_W2, c1_b2, uA, E, N, B);
        finalize_kernel<<<agrid, 256, 0, stream>>>(uA, aggTotal);

        hipMemsetAsync(uB, 0xFF, aggBytes, stream);
        edge_conv_kernel<8><<<egrid, 256, 0, stream>>>(
            (const float*)uA, ei, ea, c2_W1, c2_b1, c2_W2, c2_b2, uB, E, N, B);
        finalize_kernel<<<agrid, 256, 0, stream>>>(uB, aggTotal);

        hipMemsetAsync(uA, 0xFF, aggBytes, stream);
        edge_conv_kernel<8><<<egrid, 256, 0, stream>>>(
            (const float*)uB, ei, ea, c3_W1, c3_b1, c3_W2, c3_b2, uA, E, N, B);
        finalize_kernel<<<agrid, 256, 0, stream>>>(uA, aggTotal);

        dim3 pgrid((N + 255) / 256, B);
        pool_kernel<<<pgrid, 256, 0, stream>>>(x0, (const float*)uA, lw, lb, out, N);
    }
}

// Round 9
// 218.731 us; speedup vs baseline: 11.7607x; 1.0233x over previous
//
#include <hip/hip_runtime.h>

#define LEAK 0.01f
#define BS 128           // nodes per bucket (dl fits in 7 bits)
#define PCHUNK 8192      // edges per partition chunk (contiguous 64KB pair window)
#define PT 512           // threads for part (8 waves)
#define CT 512           // threads for conv kernels
#define MAXNB 1024       // max buckets per graph (= 2*PT, scan invariant)
#define CPGMAX 256       // max chunks per graph (conv LDS run arrays)

__device__ __forceinline__ float lrelu(float v) {
    return v >= 0.f ? v : LEAK * v;
}

// ---- float <-> orderable-uint encoding for min (inf -> 0xFFFFFFFF) ----
__device__ __forceinline__ unsigned int fmin_encode(float x) {
    unsigned int u = __float_as_uint(x);
    return (u & 0x80000000u) ? ~u : (u | 0x80000000u);
}
__device__ __forceinline__ float fmin_decode(unsigned int k) {
    unsigned int u = (k & 0x80000000u) ? (k ^ 0x80000000u) : ~k;
    return __uint_as_float(u);
}

// block-reduce (any multiple-of-64 block) + one atomicAdd
__device__ __forceinline__ void block_add(float c, float* dst) {
    __shared__ float wsum[8];
#pragma unroll
    for (int off = 32; off > 0; off >>= 1) c += __shfl_down(c, off, 64);
    int lane = threadIdx.x & 63;
    int wave = threadIdx.x >> 6;
    if (lane == 0) wsum[wave] = c;
    __syncthreads();
    if (threadIdx.x == 0) {
        float s = 0.f;
        int nw = blockDim.x >> 6;
        for (int w = 0; w < nw; ++w) s += wsum[w];
        atomicAdd(dst, s);
    }
}

// ---------------------------------------------------------------------------
// init + layer-1 precompute + x0 pool contribution (x0 never materialized)
// ---------------------------------------------------------------------------
__global__ __launch_bounds__(256) void init_pre1_kernel(
    const int* __restrict__ nf, const float* __restrict__ act,
    const float* __restrict__ W1, const float* __restrict__ b1,
    const float* __restrict__ lw, const float* __restrict__ lb,
    float* __restrict__ a1, float* __restrict__ a2,
    float* __restrict__ out, int N) {
    int b = blockIdx.y;
    int n = blockIdx.x * 256 + threadIdx.x;
    float c = 0.f;
    if (n < N) {
        size_t i = (size_t)b * N + n;
        float x0 = (float)nf[i * 2 + 0];
        float x1 = (float)nf[i * 2 + 1];
        float x2 = act[i];
        float v1[8], v2[8];
#pragma unroll
        for (int j = 0; j < 8; ++j) {
            v1[j] = b1[j] + x0 * W1[0 * 8 + j] + x1 * W1[1 * 8 + j] + x2 * W1[2 * 8 + j];
            v2[j] =         x0 * W1[3 * 8 + j] + x1 * W1[4 * 8 + j] + x2 * W1[5 * 8 + j];
        }
        float4* o1 = (float4*)(a1 + i * 8);
        float4* o2 = (float4*)(a2 + i * 8);
        o1[0] = make_float4(v1[0], v1[1], v1[2], v1[3]);
        o1[1] = make_float4(v1[4], v1[5], v1[6], v1[7]);
        o2[0] = make_float4(v2[0], v2[1], v2[2], v2[3]);
        o2[1] = make_float4(v2[4], v2[5], v2[6], v2[7]);
        c = x0 * lw[0] + x1 * lw[1] + x2 * lw[2];
        if (n == 0) c += lb[0];
    }
    block_add(c, &out[b]);
}

// ---------------------------------------------------------------------------
// one-pass chunk-local partition: LDS hist (rank per edge) -> LDS scan ->
// chunk-major coalesced pair write + per-chunk bin offsets (ofs).
// pair = { src | dl<<16 , ea_bits }; no global hist/scan needed.
// ---------------------------------------------------------------------------
__global__ __launch_bounds__(PT) void part_kernel(
    const int* __restrict__ ei, const float* __restrict__ ea,
    int2* __restrict__ pairs, int* __restrict__ ofs,
    int E, int NB, int CPG) {
    __shared__ int lc[MAXNB];        // hist counts, then run starts (cursor-free)
    __shared__ int lofs[MAXNB + 1];  // exclusive starts
    __shared__ int ts[PT];           // scan temp
    int b = blockIdx.y;
    int c = blockIdx.x;
    int t = threadIdx.x;
    for (int i = t; i < NB; i += PT) lc[i] = 0;
    __syncthreads();

    int e0 = c * PCHUNK;
    int end = min(e0 + PCHUNK, E);
    const int* srow = ei + (size_t)b * 2 * E;
    const int* drow = srow + E;

    // phase 1: hist with per-edge rank capture
    int pk[PCHUNK / PT];  // bin | dl<<10 | rank<<17
#pragma unroll
    for (int j = 0; j < PCHUNK / PT; ++j) {
        int e = e0 + j * PT + t;
        int p = -1;
        if (e < end) {
            int d = drow[e];
            int bin = d >> 7;
            int r = atomicAdd(&lc[bin], 1);
            p = bin | ((d & 127) << 10) | (r << 17);
        }
        pk[j] = p;
    }
    __syncthreads();

    // phase 2: exclusive scan over NB bins (thread t owns bins 2t, 2t+1)
    int bin0 = 2 * t, bin1 = 2 * t + 1;
    int v0 = (bin0 < NB) ? lc[bin0] : 0;
    int v1 = (bin1 < NB) ? lc[bin1] : 0;
    int s = v0 + v1;
    ts[t] = s;
    __syncthreads();
    int incl = s;
    for (int off = 1; off < PT; off <<= 1) {
        int add = (t >= off) ? ts[t - off] : 0;
        __syncthreads();
        incl += add;
        ts[t] = incl;
        __syncthreads();
    }
    int ex = incl - s;
    if (bin0 < NB) lofs[bin0] = ex;
    if (bin1 < NB) lofs[bin1] = ex + v0;
    if (t == PT - 1) lofs[NB] = incl;  // = end - e0
    __syncthreads();

    // export ofs + set run starts
    int* og = ofs + ((size_t)b * CPG + c) * (NB + 1);
    for (int i = t; i <= NB; i += PT) {
        int v = lofs[i];
        og[i] = v;
        if (i < NB) lc[i] = v;
    }
    __syncthreads();

    // phase 3: coalesced-window pair write (pos = start + rank, no atomics)
    size_t pbase = (size_t)b * E + e0;
#pragma unroll
    for (int j = 0; j < PCHUNK / PT; ++j) {
        int e = e0 + j * PT + t;
        if (e < end) {
            int p = pk[j];
            int bin = p & 1023;
            int dl = (p >> 10) & 127;
            int r = p >> 17;
            int pos = lc[bin] + r;
            pairs[pbase + pos] =
                make_int2(srow[e] | (dl << 16), __float_as_int(ea[(size_t)b * E + e]));
        }
    }
}

// ---------------------------------------------------------------------------
// bucket conv: one block per 128-node bucket, runs iterated wave-per-run,
// LDS encoded-uint min accumulator
// ---------------------------------------------------------------------------

__device__ __forceinline__ void conv_edge_body(
    const float* __restrict__ a2g, const float* we, const float* bb,
    const float* __restrict__ W2, int2 p,
    const float* __restrict__ a1s, unsigned int* __restrict__ acc) {
    int srcn = p.x & 0xFFFF;
    int dl = (p.x >> 16) & 127;
    float eav = __int_as_float(p.y);
    const float4* q = (const float4*)(a2g + (size_t)srcn * 8);
    float4 lo = q[0], hi = q[1];
    float h1[8];
    h1[0] = a1s[dl * 9 + 0] + lo.x; h1[1] = a1s[dl * 9 + 1] + lo.y;
    h1[2] = a1s[dl * 9 + 2] + lo.z; h1[3] = a1s[dl * 9 + 3] + lo.w;
    h1[4] = a1s[dl * 9 + 4] + hi.x; h1[5] = a1s[dl * 9 + 5] + hi.y;
    h1[6] = a1s[dl * 9 + 6] + hi.z; h1[7] = a1s[dl * 9 + 7] + hi.w;
#pragma unroll
    for (int j = 0; j < 8; ++j) {
        h1[j] = fmaf(eav, we[j], h1[j]);
        h1[j] = lrelu(h1[j]);
    }
    float h2[8];
#pragma unroll
    for (int j = 0; j < 8; ++j) h2[j] = bb[j];
#pragma unroll
    for (int kk = 0; kk < 8; ++kk) {
        float hk = h1[kk];
#pragma unroll
        for (int j = 0; j < 8; ++j) h2[j] = fmaf(hk, W2[kk * 8 + j], h2[j]);
    }
#pragma unroll
    for (int j = 0; j < 8; ++j)
        atomicMin(&acc[dl * 9 + j], fmin_encode(h2[j]));
}

// iterate this bucket's run in every chunk; wave w takes runs w, w+NW, ...
__device__ __forceinline__ void conv_edges_runs(
    const float* __restrict__ a2g, const float* we, const float* bb,
    const float* __restrict__ W2, const int2* __restrict__ pairsg,
    const int* __restrict__ ofsg, int bin, int NB, int CPG,
    const float* __restrict__ a1s, unsigned int* __restrict__ acc,
    int* __restrict__ rs, int* __restrict__ re) {
    int t = threadIdx.x;
    for (int c = t; c < CPG; c += CT) {
        const int* o = ofsg + (size_t)c * (NB + 1) + bin;
        rs[c] = o[0];
        re[c] = o[1];
    }
    __syncthreads();
    int wave = t >> 6, lane = t & 63;
    const int nw = CT >> 6;
    for (int c = wave; c < CPG; c += nw) {
        int cb = c * PCHUNK;
        int k1 = cb + re[c];
        for (int k = cb + rs[c] + lane; k < k1; k += 64)
            conv_edge_body(a2g, we, bb, W2, pairsg[k], a1s, acc);
    }
}

// conv + next-layer precompute epilogue (h never hits HBM)
__global__ __launch_bounds__(CT) void conv_mid_kernel(
    const float* __restrict__ a1, const float* __restrict__ a2,
    const float* __restrict__ w1e, const float* __restrict__ W2,
    const float* __restrict__ b2,
    const float* __restrict__ nW1, const float* __restrict__ nb1,
    const int* __restrict__ ofs, const int2* __restrict__ pairs,
    float* __restrict__ na1, float* __restrict__ na2,
    int N, int NB, int CPG, int E) {
    __shared__ float a1s[BS * 9];
    __shared__ unsigned int acc[BS * 9];
    __shared__ int rs[CPGMAX];
    __shared__ int re[CPGMAX];
    int b = blockIdx.y;
    int bin = blockIdx.x;
    int n0 = bin << 7;
    int nCnt = min(BS, N - n0);
    int t = threadIdx.x;
    size_t gn0 = ((size_t)b * N + n0) * 8;

    for (int i = t; i < nCnt * 8; i += CT)
        a1s[(i >> 3) * 9 + (i & 7)] = a1[gn0 + i];
    for (int i = t; i < BS * 9; i += CT) acc[i] = 0xFFFFFFFFu;
    float we[8], bb[8];
#pragma unroll
    for (int j = 0; j < 8; ++j) { we[j] = w1e[j]; bb[j] = b2[j]; }
    __syncthreads();

    conv_edges_runs(a2 + (size_t)b * N * 8, we, bb, W2,
                    pairs + (size_t)b * E, ofs + (size_t)b * CPG * (NB + 1),
                    bin, NB, CPG, a1s, acc, rs, re);
    __syncthreads();

    // decode h into a1s (reuse)
    for (int i = t; i < nCnt * 8; i += CT) {
        float v = fmin_decode(acc[(i >> 3) * 9 + (i & 7)]);
        unsigned int u = __float_as_uint(v);
        if ((u & 0x7F800000u) == 0x7F800000u) v = 0.f;
        a1s[(i >> 3) * 9 + (i & 7)] = lrelu(v);
    }
    __syncthreads();

    // next-layer precompute: 2 threads per node (half 0 -> a1', half 1 -> a2')
    int node = t >> 1, half = t & 1;
    if (node < nCnt) {
        float h[8];
#pragma unroll
        for (int j = 0; j < 8; ++j) h[j] = a1s[node * 9 + j];
        float v[8];
#pragma unroll
        for (int j = 0; j < 8; ++j) v[j] = half ? 0.f : nb1[j];
        const float* Wbase = nW1 + (half ? 64 : 0);
#pragma unroll
        for (int k = 0; k < 8; ++k) {
            float hk = h[k];
#pragma unroll
            for (int j = 0; j < 8; ++j) v[j] = fmaf(hk, Wbase[k * 8 + j], v[j]);
        }
        float* dst = (half ? na2 : na1) + gn0 + (size_t)node * 8;
        float4* o = (float4*)dst;
        o[0] = make_float4(v[0], v[1], v[2], v[3]);
        o[1] = make_float4(v[4], v[5], v[6], v[7]);
    }
}

// final conv: epilogue folds h·lw[3:11] into out[b]
__global__ __launch_bounds__(CT) void conv_final_kernel(
    const float* __restrict__ a1, const float* __restrict__ a2,
    const float* __restrict__ w1e, const float* __restrict__ W2,
    const float* __restrict__ b2, const float* __restrict__ lw,
    const int* __restrict__ ofs, const int2* __restrict__ pairs,
    float* __restrict__ out, int N, int NB, int CPG, int E) {
    __shared__ float a1s[BS * 9];
    __shared__ unsigned int acc[BS * 9];
    __shared__ int rs[CPGMAX];
    __shared__ int re[CPGMAX];
    int b = blockIdx.y;
    int bin = blockIdx.x;
    int n0 = bin << 7;
    int nCnt = min(BS, N - n0);
    int t = threadIdx.x;
    size_t gn0 = ((size_t)b * N + n0) * 8;

    for (int i = t; i < nCnt * 8; i += CT)
        a1s[(i >> 3) * 9 + (i & 7)] = a1[gn0 + i];
    for (int i = t; i < BS * 9; i += CT) acc[i] = 0xFFFFFFFFu;
    float we[8], bb[8];
#pragma unroll
    for (int j = 0; j < 8; ++j) { we[j] = w1e[j]; bb[j] = b2[j]; }
    __syncthreads();

    conv_edges_runs(a2 + (size_t)b * N * 8, we, bb, W2,
                    pairs + (size_t)b * E, ofs + (size_t)b * CPG * (NB + 1),
                    bin, NB, CPG, a1s, acc, rs, re);
    __syncthreads();

    float c = 0.f;
    if (t < nCnt) {
#pragma unroll
        for (int j = 0; j < 8; ++j) {
            float v = fmin_decode(acc[t * 9 + j]);
            unsigned int u = __float_as_uint(v);
            if ((u & 0x7F800000u) == 0x7F800000u) v = 0.f;
            c = fmaf(lrelu(v), lw[3 + j], c);
        }
    }
    __syncthreads();
    block_add(c, &out[b]);
}

// ---------------------------------------------------------------------------
// fallback (R3 proven path): per-edge atomic scatter-min
// ---------------------------------------------------------------------------

__global__ __launch_bounds__(256) void node_init_kernel(
    const int* __restrict__ nf, const float* __restrict__ act,
    float* __restrict__ x0, int BN) {
    int tid = blockIdx.x * blockDim.x + threadIdx.x;
    if (tid >= BN) return;
    x0[tid * 3 + 0] = (float)nf[tid * 2 + 0];
    x0[tid * 3 + 1] = (float)nf[tid * 2 + 1];
    x0[tid * 3 + 2] = act[tid];
}

template <int D>
__global__ __launch_bounds__(256) void edge_conv_kernel(
    const float* __restrict__ x, const int* __restrict__ ei,
    const float* __restrict__ ea,
    const float* __restrict__ W1, const float* __restrict__ b1,
    const float* __restrict__ W2, const float* __restrict__ b2,
    unsigned int* __restrict__ agg, int E, int N, int B) {
    int tid = blockIdx.x * blockDim.x + threadIdx.x;
    if (tid >= B * E) return;
    int b = tid / E;
    int e = tid - b * E;
    const int* eb = ei + (size_t)b * 2 * E;
    int s = eb[e];
    int d = eb[E + e];
    const float* xi = x + ((size_t)b * N + d) * D;
    const float* xj = x + ((size_t)b * N + s) * D;
    constexpr int M = 2 * D + 1;
    float m[M];
#pragma unroll
    for (int k = 0; k < D; ++k) { m[k] = xi[k]; m[D + k] = xj[k]; }
    m[2 * D] = ea[(size_t)b * E + e];
    float h1[8];
#pragma unroll
    for (int j = 0; j < 8; ++j) h1[j] = b1[j];
#pragma unroll
    for (int k = 0; k < M; ++k) {
        float mk = m[k];
#pragma unroll
        for (int j = 0; j < 8; ++j) h1[j] = fmaf(mk, W1[k * 8 + j], h1[j]);
    }
#pragma unroll
    for (int j = 0; j < 8; ++j) h1[j] = lrelu(h1[j]);
    float h2[8];
#pragma unroll
    for (int j = 0; j < 8; ++j) h2[j] = b2[j];
#pragma unroll
    for (int k = 0; k < 8; ++k) {
        float hk = h1[k];
#pragma unroll
        for (int j = 0; j < 8; ++j) h2[j] = fmaf(hk, W2[k * 8 + j], h2[j]);
    }
    unsigned int* ag = agg + ((size_t)b * N + d) * 8;
#pragma unroll
    for (int j = 0; j < 8; ++j) atomicMin(&ag[j], fmin_encode(h2[j]));
}

__global__ __launch_bounds__(256) void finalize_kernel(
    unsigned int* __restrict__ agg, int total) {
    int tid = blockIdx.x * blockDim.x + threadIdx.x;
    if (tid >= total) return;
    float v = fmin_decode(agg[tid]);
    unsigned int u = __float_as_uint(v);
    if ((u & 0x7F800000u) == 0x7F800000u) v = 0.f;
    ((float*)agg)[tid] = lrelu(v);
}

__global__ __launch_bounds__(256) void pool_kernel(
    const float* __restrict__ x0, const float* __restrict__ h,
    const float* __restrict__ lw, const float* __restrict__ lb,
    float* __restrict__ out, int N) {
    int b = blockIdx.y;
    int n = blockIdx.x * blockDim.x + threadIdx.x;
    float c = 0.f;
    if (n < N) {
        const float* x = x0 + ((size_t)b * N + n) * 3;
        const float* hh = h + ((size_t)b * N + n) * 8;
        c = x[0] * lw[0] + x[1] * lw[1] + x[2] * lw[2];
#pragma unroll
        for (int k = 0; k < 8; ++k) c = fmaf(hh[k], lw[3 + k], c);
        if (n == 0) c += lb[0];
    }
    block_add(c, &out[b]);
}

// ---------------------------------------------------------------------------

static inline size_t align256(size_t x) { return (x + 255) & ~(size_t)255; }

extern "C" void kernel_launch(void* const* d_in, const int* in_sizes, int n_in,
                              void* d_out, int out_size, void* d_ws, size_t ws_size,
                              hipStream_t stream) {
    const int B = 4;
    const int N = in_sizes[1] / B;            // actions [B,N]
    const int E = in_sizes[2] / (2 * B);      // edge_index [B,2,E]

    const int*   nf  = (const int*)d_in[0];
    const float* act = (const float*)d_in[1];
    const int*   ei  = (const int*)d_in[2];   // int32 (JAX x64 disabled)
    const float* ea  = (const float*)d_in[3];
    const float* c1_W1 = (const float*)d_in[4];
    const float* c1_b1 = (const float*)d_in[5];
    const float* c1_W2 = (const float*)d_in[6];
    const float* c1_b2 = (const float*)d_in[7];
    const float* c2_W1 = (const float*)d_in[8];
    const float* c2_b1 = (const float*)d_in[9];
    const float* c2_W2 = (const float*)d_in[10];
    const float* c2_b2 = (const float*)d_in[11];
    const float* c3_W1 = (const float*)d_in[12];
    const float* c3_b1 = (const float*)d_in[13];
    const float* c3_W2 = (const float*)d_in[14];
    const float* c3_b2 = (const float*)d_in[15];
    const float* lw    = (const float*)d_in[16];
    const float* lb    = (const float*)d_in[17];
    float* out = (float*)d_out;

    const int BN = B * N;
    const int BE = B * E;
    const int NB = (N + BS - 1) / BS;         // buckets per graph
    const int CPG = (E + PCHUNK - 1) / PCHUNK;

    // ---- workspace layout ----
    char* ws = (char*)d_ws;
    size_t off = 0;
    float* a1A  = (float*)(ws + off);  off += align256((size_t)BN * 8 * 4);
    float* a2A  = (float*)(ws + off);  off += align256((size_t)BN * 8 * 4);
    float* a1B  = (float*)(ws + off);  off += align256((size_t)BN * 8 * 4);
    float* a2B  = (float*)(ws + off);  off += align256((size_t)BN * 8 * 4);
    int* ofs    = (int*)(ws + off);    off += align256((size_t)B * CPG * (NB + 1) * 4);
    int2* pairs = (int2*)(ws + off);   off += align256((size_t)BE * 8);
    // fallback extras
    float* x0   = (float*)(ws + off);  off += align256((size_t)BN * 3 * 4);
    const bool useFast = (off <= ws_size) && (NB <= MAXNB) && (CPG <= CPGMAX) &&
                         (N <= 65536);

    hipMemsetAsync(out, 0, (size_t)B * sizeof(float), stream);

    if (useFast) {
        dim3 pgrid(CPG, B);
        dim3 igrid((N + 255) / 256, B);
        dim3 cgrid(NB, B);

        init_pre1_kernel<<<igrid, 256, 0, stream>>>(nf, act, c1_W1, c1_b1,
                                                    lw, lb, a1A, a2A, out, N);
        part_kernel<<<pgrid, PT, 0, stream>>>(ei, ea, pairs, ofs, E, NB, CPG);

        // conv1: a1A/a2A -> (epilogue pre2) a1B/a2B
        conv_mid_kernel<<<cgrid, CT, 0, stream>>>(
            a1A, a2A, c1_W1 + 6 * 8, c1_W2, c1_b2, c2_W1, c2_b1,
            ofs, pairs, a1B, a2B, N, NB, CPG, E);
        // conv2: a1B/a2B -> (epilogue pre3) a1A/a2A
        conv_mid_kernel<<<cgrid, CT, 0, stream>>>(
            a1B, a2B, c2_W1 + 16 * 8, c2_W2, c2_b2, c3_W1, c3_b1,
            ofs, pairs, a1A, a2A, N, NB, CPG, E);
        // conv3: a1A/a2A -> out (pool fold)
        conv_final_kernel<<<cgrid, CT, 0, stream>>>(
            a1A, a2A, c3_W1 + 16 * 8, c3_W2, c3_b2, lw,
            ofs, pairs, out, N, NB, CPG, E);
    } else {
        // ---- fallback: R3 proven atomic path ----
        const int egrid = (BE + 255) / 256;
        const int aggTotal = BN * 8;
        const int agrid = (aggTotal + 255) / 256;
        const size_t aggBytes = (size_t)aggTotal * 4;
        unsigned int* uA = (unsigned int*)a1A;
        unsigned int* uB = (unsigned int*)a1B;

        node_init_kernel<<<(BN + 255) / 256, 256, 0, stream>>>(nf, act, x0, BN);

        hipMemsetAsync(uA, 0xFF, aggBytes, stream);
        edge_conv_kernel<3><<<egrid, 256, 0, stream>>>(
            x0, ei, ea, c1_W1, c1_b1, c1_W2, c1_b2, uA, E, N, B);
        finalize_kernel<<<agrid, 256, 0, stream>>>(uA, aggTotal);

        hipMemsetAsync(uB, 0xFF, aggBytes, stream);
        edge_conv_kernel<8><<<egrid, 256, 0, stream>>>(
            (const float*)uA, ei, ea, c2_W1, c2_b1, c2_W2, c2_b2, uB, E, N, B);
        finalize_kernel<<<agrid, 256, 0, stream>>>(uB, aggTotal);

        hipMemsetAsync(uA, 0xFF, aggBytes, stream);
        edge_conv_kernel<8><<<egrid, 256, 0, stream>>>(
            (const float*)uB, ei, ea, c3_W1, c3_b1, c3_W2, c3_b2, uA, E, N, B);
        finalize_kernel<<<agrid, 256, 0, stream>>>(uA, aggTotal);

        dim3 plgrid((N + 255) / 256, B);
        pool_kernel<<<plgrid, 256, 0, stream>>>(x0, (const float*)uA, lw, lb, out, N);
    }
}